// Round 5
// baseline (1731.607 us; speedup 1.0000x reference)
//
#include <hip/hip_runtime.h>
#include <hip/hip_fp16.h>

#define BB 1024
#define SS 128
#define FF 64
#define HH 100

typedef _Float16 h8 __attribute__((ext_vector_type(8)));
typedef float f4v __attribute__((ext_vector_type(4)));

__device__ __forceinline__ float sigmf(float x){ return 1.0f/(1.0f+__expf(-x)); }
// fast tanh: exact at +-inf, ~1e-6 abs error; ~5 ops vs ~40 for libm tanhf
__device__ __forceinline__ float ftanh(float x){ float e=__expf(2.f*x); return 1.f - 2.f/(e+1.f); }

__device__ __forceinline__ float wsum(float v){
#pragma unroll
  for (int m = 32; m >= 1; m >>= 1) v += __shfl_xor(v, m, 64);
  return v;
}
__device__ __forceinline__ float wmax(float v){
#pragma unroll
  for (int m = 32; m >= 1; m >>= 1) v = fmaxf(v, __shfl_xor(v, m, 64));
  return v;
}

// ---------------- gram: gram[b,i,j] = sum_s x[b,s,i]*x[b,s,j] ----------------
__global__ __launch_bounds__(256) void k_gram(const float* __restrict__ x, float* __restrict__ gram){
  __shared__ __align__(16) float xs[SS*FF];
  int b = blockIdx.x, tid = threadIdx.x;
  const float* xb = x + (size_t)b*SS*FF;
  for (int i = tid; i < SS*FF/4; i += 256)
    ((float4*)xs)[i] = ((const float4*)xb)[i];
  __syncthreads();
  int ti = (tid & 15) * 4, tj = (tid >> 4) * 4;
  float acc[4][4];
#pragma unroll
  for (int a=0;a<4;++a)
#pragma unroll
    for (int c=0;c<4;++c) acc[a][c]=0.f;
  for (int s = 0; s < SS; ++s) {
    const float* row = xs + s*FF;
    float4 av = *(const float4*)(row + ti);
    float4 bv = *(const float4*)(row + tj);
    float aa[4] = {av.x,av.y,av.z,av.w};
    float bb2[4] = {bv.x,bv.y,bv.z,bv.w};
#pragma unroll
    for (int a=0;a<4;++a)
#pragma unroll
      for (int c=0;c<4;++c) acc[a][c] += aa[a]*bb2[c];
  }
  float* g = gram + (size_t)b*4096;
#pragma unroll
  for (int a=0;a<4;++a)
#pragma unroll
    for (int c=0;c<4;++c) g[(ti+a)*64 + tj + c] = acc[a][c];
}

// ------- conv1(3x3,1->16,SAME)+bias+relu+maxpool2 -> half CHANNEL-LAST [B][p][ic] -------
__global__ __launch_bounds__(256) void k_conv1pool(const float* __restrict__ gram,
    const float* __restrict__ c1w, const float* __restrict__ c1b, __half* __restrict__ pool1){
  __shared__ float img2[66*66];
  __shared__ float ws1[144];
  __shared__ float bs1[16];
  int tid=threadIdx.x, b=blockIdx.x;
  for (int i=tid;i<66*66;i+=256) img2[i]=0.f;
  if (tid<144) ws1[tid]=c1w[tid];
  if (tid<16) bs1[tid]=c1b[tid];
  __syncthreads();
  const float* gb = gram + (size_t)b*4096;
  for (int i=tid;i<4096;i+=256){ int y=i>>6, xx=i&63; img2[(y+1)*66 + xx+1] = gb[i]; }
  __syncthreads();
  int oc = tid>>4, slot = tid&15;
  float wr[9];
#pragma unroll
  for (int t=0;t<9;++t) wr[t]=ws1[oc*9+t];
  float bo = bs1[oc];
  for (int p=slot;p<1024;p+=16){
    int py=p>>5, px=p&31;
    int y0=py*2, x0=px*2;
    float v[4][4];
#pragma unroll
    for (int wy=0;wy<4;++wy)
#pragma unroll
      for (int wxx=0;wxx<4;++wxx) v[wy][wxx]=img2[(y0+wy)*66 + x0+wxx];
    float s00=bo,s01=bo,s10=bo,s11=bo;
#pragma unroll
    for (int ky=0;ky<3;++ky)
#pragma unroll
      for (int kx=0;kx<3;++kx){
        float w=wr[ky*3+kx];
        s00 += v[ky][kx]*w;   s01 += v[ky][kx+1]*w;
        s10 += v[ky+1][kx]*w; s11 += v[ky+1][kx+1]*w;
      }
    float mx = fmaxf(fmaxf(s00,s01),fmaxf(s10,s11));
    pool1[(size_t)b*16384 + p*16 + oc] = __float2half(fmaxf(mx,0.f));
  }
}

// ================= conv2 as implicit-im2col MFMA GEMM =================
__global__ __launch_bounds__(512, 4) void k_conv2mfma(const __half* __restrict__ pool1,
    const float* __restrict__ c2w, const float* __restrict__ c2b, float* __restrict__ proc){
  __shared__ __align__(16) _Float16 img[(34*34+1)*24];   // +1 zero slot
  __shared__ float red[8][32];
  int b = blockIdx.x, tid = threadIdx.x;
  int wv = tid>>6, l = tid&63, lm = l&15, lq = l>>4;
  h8 bfr[2][5];
  float biasv[2];
#pragma unroll
  for (int nt=0; nt<2; ++nt){
    int oc = nt*16 + lm;
    biasv[nt] = c2b[oc];
#pragma unroll
    for (int c=0;c<5;++c){
      h8 f;
#pragma unroll
      for (int j=0;j<8;++j){
        int k = c*32 + lq*8 + j;
        int tap = k>>4, ic = k&15;
        f[j] = (_Float16)((tap<9) ? c2w[oc*144 + ic*9 + tap] : 0.f);
      }
      bfr[nt][c]=f;
    }
  }
  {
    h8 z = {0,0,0,0,0,0,0,0};
    for (int i=tid; i<(34*34+1)*3; i+=512) ((h8*)img)[i] = z;
  }
  __syncthreads();
  const __half* src = pool1 + (size_t)b*16384;
  for (int pp=tid; pp<1024; pp+=512){
    int y=pp>>5, x=pp&31;
    const h8* s = (const h8*)(src + pp*16);
    h8* d = (h8*)&img[((y+1)*34 + (x+1))*24];
    d[0]=s[0]; d[1]=s[1];
  }
  __syncthreads();
  f4v ssum0 = {0,0,0,0}, ssum1 = {0,0,0,0};
#pragma unroll 2
  for (int i=0;i<8;++i){
    int mt = wv + i*8;
    int y = mt>>1, x0 = (mt&1)*16;
    h8 afr[5];
#pragma unroll
    for (int c=0;c<5;++c){
      int tap = 2*c + (lq>>1);
      int addr;
      if (c==4 && lq>=2) addr = 34*34*24;
      else {
        int dy = tap/3 - 1, dx = tap - (tap/3)*3 - 1;
        addr = ((y+dy+1)*34 + (x0+lm+dx+1))*24 + (lq&1)*8;
      }
      afr[c] = *(const h8*)&img[addr];
    }
    f4v a0 = {biasv[0],biasv[0],biasv[0],biasv[0]};
    f4v a1 = {biasv[1],biasv[1],biasv[1],biasv[1]};
#pragma unroll
    for (int c=0;c<5;++c){
      a0 = __builtin_amdgcn_mfma_f32_16x16x32_f16(afr[c], bfr[0][c], a0, 0,0,0);
      a1 = __builtin_amdgcn_mfma_f32_16x16x32_f16(afr[c], bfr[1][c], a1, 0,0,0);
    }
#pragma unroll
    for (int r=0;r<4;++r){
      ssum0[r] += fmaxf(a0[r],0.f);
      ssum1[r] += fmaxf(a1[r],0.f);
    }
  }
  float s0 = ssum0[0]+ssum0[1]+ssum0[2]+ssum0[3];
  float s1 = ssum1[0]+ssum1[1]+ssum1[2]+ssum1[3];
  s0 += __shfl_xor(s0,16,64); s0 += __shfl_xor(s0,32,64);
  s1 += __shfl_xor(s1,16,64); s1 += __shfl_xor(s1,32,64);
  if (lq==0){ red[wv][lm]=s0; red[wv][16+lm]=s1; }
  __syncthreads();
  if (tid<32){
    float t=0.f;
#pragma unroll
    for (int w2=0;w2<8;++w2) t += red[w2][tid];
    proc[b*32+tid] = t*(1.f/1024.f);
  }
}

// ------------- fs = tanh(x@fW1^T+fb1)@fW2^T+fb2, per (b,s) row -------------
__global__ __launch_bounds__(256) void k_fs(const float* __restrict__ x,
    const float* __restrict__ fW1, const float* __restrict__ fb1,
    const float* __restrict__ fW2, const float* __restrict__ fb2,
    float* __restrict__ fs){
  __shared__ float w1t[64*32];
  __shared__ float w2t[32*64];
  __shared__ float b1s[32], b2s[64];
  __shared__ __align__(16) float xbuf[4][8][64];
  __shared__ float t1buf[4][8][32];
  int tid=threadIdx.x, wv=tid>>6, lane=tid&63;
  for (int i=tid;i<2048;i+=256){ int j=i>>6,k=i&63; w1t[k*32+j]=fW1[i]; }
  for (int i=tid;i<2048;i+=256){ int j=i>>5,k=i&31; w2t[k*64+j]=fW2[i]; }
  if (tid<32) b1s[tid]=fb1[tid];
  if (tid<64) b2s[tid]=fb2[tid];
  __syncthreads();
  size_t Rw = (size_t)blockIdx.x*64 + wv*16;
  int j = lane & 31, half = lane >> 5;
  for (int pass=0; pass<2; ++pass){
    size_t R0 = Rw + pass*8;
    const float4* src = (const float4*)(x + R0*64);
    float4* dst = (float4*)&xbuf[wv][0][0];
    for (int i=lane;i<128;i+=64) dst[i]=src[i];
    __syncthreads();
    {
      float a0=b1s[j],a1=b1s[j],a2=b1s[j],a3=b1s[j];
      const float* xr = &xbuf[wv][half*4][0];
      for (int k=0;k<64;++k){
        float w = w1t[k*32+j];
        a0 += w*xr[k]; a1 += w*xr[64+k]; a2 += w*xr[128+k]; a3 += w*xr[192+k];
      }
      float* t1r = &t1buf[wv][half*4][0];
      t1r[j]=ftanh(a0); t1r[32+j]=ftanh(a1); t1r[64+j]=ftanh(a2); t1r[96+j]=ftanh(a3);
    }
    __syncthreads();
    {
      float f[8];
#pragma unroll
      for (int r=0;r<8;++r) f[r]=b2s[lane];
      for (int k=0;k<32;++k){
        float w = w2t[k*64+lane];
#pragma unroll
        for (int r=0;r<8;++r) f[r] += w*t1buf[wv][r][k];
      }
#pragma unroll
      for (int r=0;r<8;++r) fs[(R0+r)*64 + lane] = f[r];
    }
    __syncthreads();
  }
}

// ------- aw = tanh([fs,proc]@cW1^T+cb1)@cW2^T+cb2; feature_w=softmax(aw); wx=x*fw -------
__global__ __launch_bounds__(256) void k_attnmlp(const float* __restrict__ x,
    const float* __restrict__ fs, const float* __restrict__ proc,
    const float* __restrict__ cW1, const float* __restrict__ cb1,
    const float* __restrict__ cW2, const float* __restrict__ cb2,
    float* __restrict__ fw_out, float* __restrict__ wx){
  __shared__ float c1t[96*64];
  __shared__ float c2t[64*64];
  __shared__ float cb1s[64], cb2s[64];
  __shared__ float cmb[4][4][96];
  __shared__ float h2b[4][4][64];
  int tid = threadIdx.x, wv = tid>>6, lane = tid&63;
  for (int i = tid; i < 6144; i += 256){ int j = i/96, k = i%96; c1t[k*64+j] = cW1[i]; }
  for (int i = tid; i < 4096; i += 256){ int j = i>>6, k = i&63; c2t[k*64+j] = cW2[i]; }
  if (tid < 64) { cb1s[tid] = cb1[tid]; cb2s[tid] = cb2[tid]; }
  __syncthreads();
  size_t Rw = (size_t)blockIdx.x*64 + wv*16;
  for (int pass = 0; pass < 4; ++pass) {
    size_t R0 = Rw + pass*4;
    for (int i = lane; i < 384; i += 64) {
      int r = i/96, k = i%96;
      size_t R = R0 + r;
      cmb[wv][r][k] = (k < 64) ? fs[R*64 + k] : proc[(R>>7)*32 + (k-64)];
    }
    __syncthreads();
    float h0a=cb1s[lane],h1a=cb1s[lane],h2a=cb1s[lane],h3a=cb1s[lane];
    for (int k = 0; k < 96; ++k) {
      float w = c1t[k*64+lane];
      h0a += w*cmb[wv][0][k]; h1a += w*cmb[wv][1][k];
      h2a += w*cmb[wv][2][k]; h3a += w*cmb[wv][3][k];
    }
    h2b[wv][0][lane]=ftanh(h0a); h2b[wv][1][lane]=ftanh(h1a);
    h2b[wv][2][lane]=ftanh(h2a); h2b[wv][3][lane]=ftanh(h3a);
    __syncthreads();
    float a0=cb2s[lane],a1=cb2s[lane],a2=cb2s[lane],a3=cb2s[lane];
    for (int k = 0; k < 64; ++k) {
      float w = c2t[k*64+lane];
      a0 += w*h2b[wv][0][k]; a1 += w*h2b[wv][1][k];
      a2 += w*h2b[wv][2][k]; a3 += w*h2b[wv][3][k];
    }
    float m0=wmax(a0), m1=wmax(a1), m2=wmax(a2), m3=wmax(a3);
    float e0=__expf(a0-m0), e1=__expf(a1-m1), e2=__expf(a2-m2), e3=__expf(a3-m3);
    float s0=wsum(e0), s1=wsum(e1), s2=wsum(e2), s3=wsum(e3);
    float f0v=e0/s0, f1v=e1/s1, f2v=e2/s2, f3v=e3/s3;
    size_t R;
    R=R0+0; fw_out[R*64+lane]=f0v; wx[R*64+lane]=x[R*64+lane]*f0v;
    R=R0+1; fw_out[R*64+lane]=f1v; wx[R*64+lane]=x[R*64+lane]*f1v;
    R=R0+2; fw_out[R*64+lane]=f2v; wx[R*64+lane]=x[R*64+lane]*f2v;
    R=R0+3; fw_out[R*64+lane]=f3v; wx[R*64+lane]=x[R*64+lane]*f3v;
    __syncthreads();
  }
}

// ================= MFMA encoder LSTM, 2 interleaved batch groups =================
// 32 blocks x 448 threads. Block owns 32 batch rows as TWO independent 16-row
// groups; each wave runs both groups' ds_read->MFMA->elementwise chains per
// step (ILP fills the latency stalls that made the 1-group version 4690
// cyc/step at 3.5% MfmaUtil). Weights (B-frags) shared across groups in VGPRs.
// Anti-NaN: ALL hbuf phases pre-zeroed; padding units (>=100) never written.
__global__ __launch_bounds__(448, 2) void k_enc_mfma(const float* __restrict__ wx,
    const float* __restrict__ Wih, const float* __restrict__ Whh,
    const float* __restrict__ bih, const float* __restrict__ bhh,
    float* __restrict__ enc){
  __shared__ __align__(16) _Float16 hbuf[2][2][16*128];   // [group][phase]
  __shared__ __align__(16) _Float16 xst[2][2][16*64];     // [group][phase]
  int tid = threadIdx.x;
  int w = tid >> 6, l = tid & 63;
  int lm = l & 15, lq = l >> 4;
  int b0 = blockIdx.x * 32;
  // ---- B fragments (shared by both groups) ----
  h8 bfr[4][6];
  float biasv[4];
  int uu = w*16 + lm;
  bool uvalid = uu < 100;
#pragma unroll
  for (int tt = 0; tt < 4; ++tt) {
    int row = tt*100 + uu;
    biasv[tt] = uvalid ? (bih[row] + bhh[row]) : 0.f;
#pragma unroll
    for (int cc = 0; cc < 6; ++cc) {
      h8 f;
#pragma unroll
      for (int j = 0; j < 8; ++j) {
        int kg = cc*32 + lq*8 + j;
        float v = 0.f;
        if (uvalid) {
          if (kg < 64) v = Wih[(size_t)row*64 + kg];
          else { int kh = kg - 64; if (kh < 100) v = Whh[(size_t)row*100 + kh]; }
        }
        f[j] = (_Float16)v;
      }
      bfr[tt][cc] = f;
    }
  }
  // zero ALL hbuf (both groups, both phases)
  for (int i = tid; i < 2*2*16*128; i += 448) ((_Float16*)hbuf)[i] = (_Float16)0.f;
  // stage x_0 for both groups (512 float4 slots over 448 threads)
  for (int i = tid; i < 512; i += 448) {
    int g = i >> 8, sm = (i >> 4) & 15, skq = i & 15;
    float4 xv0 = *(const float4*)(wx + ((size_t)(b0+g*16+sm)*SS + 0)*FF + skq*4);
    int kb = skq >> 1, j0 = (skq & 1)*4;
    _Float16* dst = &xst[g][0][sm*64 + ((kb ^ (sm & 7))<<3) + j0];
    dst[0]=(_Float16)xv0.x; dst[1]=(_Float16)xv0.y; dst[2]=(_Float16)xv0.z; dst[3]=(_Float16)xv0.w;
  }
  float cst[2][4] = {{0.f,0.f,0.f,0.f},{0.f,0.f,0.f,0.f}};
  int r0 = lq*4;
  __syncthreads();
  for (int t = 0; t < SS; ++t) {
    int cur = t & 1, nxt = cur ^ 1;
    // prefetch x_{t+1} for both groups
    float4 xpf[2];
#pragma unroll
    for (int ii = 0; ii < 2; ++ii) {
      int i = tid + ii*448;
      if (i < 512 && t < SS-1) {
        int g = i >> 8, sm = (i >> 4) & 15, skq = i & 15;
        xpf[ii] = *(const float4*)(wx + ((size_t)(b0+g*16+sm)*SS + (t+1))*FF + skq*4);
      }
    }
    // A fragments, both groups
    h8 afr[2][6];
#pragma unroll
    for (int g = 0; g < 2; ++g) {
#pragma unroll
      for (int cc = 0; cc < 2; ++cc) {
        int kb = cc*4 + lq;
        afr[g][cc] = *(const h8*)&xst[g][cur][lm*64 + ((kb ^ (lm & 7))<<3)];
      }
#pragma unroll
      for (int cc = 0; cc < 4; ++cc) {
        int kb = cc*4 + lq;
        afr[g][2+cc] = *(const h8*)&hbuf[g][cur][lm*128 + ((kb ^ (lm & 7))<<3)];
      }
    }
    // MFMA: 8 independent 6-chains (2 groups x 4 gates)
    f4v acc[2][4];
#pragma unroll
    for (int g = 0; g < 2; ++g)
#pragma unroll
      for (int tt = 0; tt < 4; ++tt) {
        f4v a = {biasv[tt], biasv[tt], biasv[tt], biasv[tt]};
#pragma unroll
        for (int cc = 0; cc < 6; ++cc)
          a = __builtin_amdgcn_mfma_f32_16x16x32_f16(afr[g][cc], bfr[tt][cc], a, 0, 0, 0);
        acc[g][tt] = a;
      }
    // elementwise + writeback
#pragma unroll
    for (int g = 0; g < 2; ++g)
#pragma unroll
      for (int r = 0; r < 4; ++r) {
        float zi = acc[g][0][r], zf = acc[g][1][r], zg = acc[g][2][r], zo = acc[g][3][r];
        float cn = sigmf(zf)*cst[g][r] + sigmf(zi)*ftanh(zg);
        float hn = sigmf(zo)*ftanh(cn);
        cst[g][r] = cn;
        int mr = r0 + r;
        if (uvalid) {
          hbuf[g][nxt][mr*128 + (((uu>>3) ^ (mr&7))<<3) + (uu&7)] = (_Float16)hn;
          enc[((size_t)(b0+g*16+mr)*SS + t)*HH + uu] = hn;
        }
      }
    // store staged x_{t+1}
#pragma unroll
    for (int ii = 0; ii < 2; ++ii) {
      int i = tid + ii*448;
      if (i < 512 && t < SS-1) {
        int g = i >> 8, sm = (i >> 4) & 15, skq = i & 15;
        int kb = skq >> 1, j0 = (skq & 1)*4;
        _Float16* dst = &xst[g][nxt][sm*64 + ((kb ^ (sm & 7))<<3) + j0];
        dst[0]=(_Float16)xpf[ii].x; dst[1]=(_Float16)xpf[ii].y;
        dst[2]=(_Float16)xpf[ii].z; dst[3]=(_Float16)xpf[ii].w;
      }
    }
    __syncthreads();
  }
}

// ------- ts/time_w softmax over S, ctx, bott, dh0, dc0, decpre; one block per batch -------
__global__ __launch_bounds__(256) void k_attn(const float* __restrict__ enc,
    const float* __restrict__ aW1, const float* __restrict__ ab1,
    const float* __restrict__ aW2, const float* __restrict__ ab2,
    const float* __restrict__ bW, const float* __restrict__ bb_,
    const float* __restrict__ h0W, const float* __restrict__ h0b,
    const float* __restrict__ c0W, const float* __restrict__ c0b,
    const float* __restrict__ dWih, const float* __restrict__ dbih, const float* __restrict__ dbhh,
    float* __restrict__ tw_out, float* __restrict__ dh0, float* __restrict__ dc0,
    float* __restrict__ decpre){
  __shared__ float a1t[100*64];
  __shared__ float a2s[64], ab1s[64];
  __shared__ float tsb[SS];
  __shared__ float ctxb[HH];
  __shared__ float bottb[32];
  __shared__ float red[8];
  int tid = threadIdx.x, wv = tid>>6, lane = tid&63;
  int b = blockIdx.x;
  const float* encb = enc + (size_t)b*SS*HH;
  for (int i=tid;i<6400;i+=256){ int jj=i/100,k=i%100; a1t[k*64+jj]=aW1[i]; }
  if (tid<64){ a2s[tid]=aW2[tid]; ab1s[tid]=ab1[tid]; }
  __syncthreads();
  float ab2v = ab2[0];
  for (int si=0; si<32; ++si){
    int s = wv*32+si;
    const float4* er = (const float4*)(encb + s*HH);
    float a = ab1s[lane];
#pragma unroll
    for (int kc=0;kc<25;++kc){
      float4 e = er[kc];
      a += e.x*a1t[(kc*4+0)*64+lane] + e.y*a1t[(kc*4+1)*64+lane]
         + e.z*a1t[(kc*4+2)*64+lane] + e.w*a1t[(kc*4+3)*64+lane];
    }
    float contrib = a2s[lane]*ftanh(a);
    float t = wsum(contrib);
    if (lane==0) tsb[s] = t + ab2v;
  }
  __syncthreads();
  float tv = (tid < SS) ? tsb[tid] : -1e30f;
  float m = wmax(tv);
  if (lane==0) red[wv]=m;
  __syncthreads();
  m = fmaxf(fmaxf(red[0],red[1]), fmaxf(red[2],red[3]));
  float e = (tid < SS) ? __expf(tv - m) : 0.f;
  float sm = wsum(e);
  if (lane==0) red[4+wv]=sm;
  __syncthreads();
  float denom = red[4]+red[5]+red[6]+red[7];
  if (tid < SS){
    float twv = e/denom;
    tw_out[(size_t)b*SS + tid] = twv;
    tsb[tid] = twv;
  }
  __syncthreads();
  if (tid < HH){
    float a = 0.f;
    for (int s=0;s<SS;++s) a += tsb[s]*encb[s*HH + tid];
    ctxb[tid]=a;
  }
  __syncthreads();
  if (tid < 32){
    float a = bb_[tid];
    const float* wr = bW + tid*HH;
    for (int k=0;k<HH;++k) a += wr[k]*ctxb[k];
    bottb[tid]=a;
  }
  __syncthreads();
  if (tid < HH){
    float a = h0b[tid];
    const float* wr = h0W + tid*32;
#pragma unroll
    for (int k=0;k<32;++k) a += wr[k]*bottb[k];
    dh0[(size_t)b*HH + tid] = a;
  } else if (tid < 200){
    int jj = tid-100;
    float a = c0b[jj];
    const float* wr = c0W + jj*32;
#pragma unroll
    for (int k=0;k<32;++k) a += wr[k]*bottb[k];
    dc0[(size_t)b*HH + jj] = a;
  }
  {
    int jj = tid;
    float a = dbih[jj]+dbhh[jj];
    const float* wr = dWih + jj*32;
#pragma unroll
    for (int k=0;k<32;++k) a += wr[k]*bottb[k];
    decpre[(size_t)b*400 + jj] = a;
    jj = tid + 256;
    if (jj < 400){
      float a2v = dbih[jj]+dbhh[jj];
      const float* wr2 = dWih + jj*32;
#pragma unroll
      for (int k=0;k<32;++k) a2v += wr2[k]*bottb[k];
      decpre[(size_t)b*400 + jj] = a2v;
    }
  }
}

// ================= MFMA decoder LSTM, 2 interleaved batch groups =================
__global__ __launch_bounds__(448, 2) void k_dec_mfma(const float* __restrict__ decpre,
    const float* __restrict__ Whh,
    const float* __restrict__ dh0, const float* __restrict__ dc0,
    float* __restrict__ dec){
  __shared__ __align__(16) _Float16 hbuf[2][2][16*128];   // [group][phase]
  int tid = threadIdx.x;
  int w = tid >> 6, l = tid & 63;
  int lm = l & 15, lq = l >> 4;
  int b0 = blockIdx.x * 32;
  int uu = w*16 + lm;
  bool uvalid = uu < 100;
  int r0 = lq*4;
  h8 bfr[4][4];
#pragma unroll
  for (int tt = 0; tt < 4; ++tt) {
    int row = tt*100 + uu;
#pragma unroll
    for (int cc = 0; cc < 4; ++cc) {
      h8 f;
#pragma unroll
      for (int j = 0; j < 8; ++j) {
        int kh = cc*32 + lq*8 + j;
        float v = (uvalid && kh < 100) ? Whh[(size_t)row*100 + kh] : 0.f;
        f[j] = (_Float16)v;
      }
      bfr[tt][cc] = f;
    }
  }
  f4v pre[2][4];
  float cst[2][4] = {{0.f,0.f,0.f,0.f},{0.f,0.f,0.f,0.f}};
#pragma unroll
  for (int g = 0; g < 2; ++g) {
#pragma unroll
    for (int tt = 0; tt < 4; ++tt)
#pragma unroll
      for (int r = 0; r < 4; ++r)
        pre[g][tt][r] = uvalid ? decpre[(size_t)(b0+g*16+r0+r)*400 + tt*100 + uu] : 0.f;
    if (uvalid) {
#pragma unroll
      for (int r = 0; r < 4; ++r) cst[g][r] = dc0[(size_t)(b0+g*16+r0+r)*HH + uu];
    }
  }
  // zero phase 1 (both groups), fill phase 0 with dh0
  for (int i = tid; i < 16*128; i += 448) { hbuf[0][1][i] = (_Float16)0.f; hbuf[1][1][i] = (_Float16)0.f; }
  for (int idx = tid; idx < 2*16*128; idx += 448) {
    int g = idx >> 11, rem = idx & 2047;
    int m = rem >> 7, u2 = rem & 127;
    float v = (u2 < 100) ? dh0[(size_t)(b0+g*16+m)*HH + u2] : 0.f;
    hbuf[g][0][m*128 + (((u2>>3) ^ (m&7))<<3) + (u2&7)] = (_Float16)v;
  }
  __syncthreads();
  for (int t = 0; t < SS; ++t) {
    int cur = t & 1, nxt = cur ^ 1;
    h8 afr[2][4];
#pragma unroll
    for (int g = 0; g < 2; ++g)
#pragma unroll
      for (int cc = 0; cc < 4; ++cc) {
        int kb = cc*4 + lq;
        afr[g][cc] = *(const h8*)&hbuf[g][cur][lm*128 + ((kb ^ (lm & 7))<<3)];
      }
    f4v acc[2][4];
#pragma unroll
    for (int g = 0; g < 2; ++g)
#pragma unroll
      for (int tt = 0; tt < 4; ++tt) {
        f4v a = pre[g][tt];
#pragma unroll
        for (int cc = 0; cc < 4; ++cc)
          a = __builtin_amdgcn_mfma_f32_16x16x32_f16(afr[g][cc], bfr[tt][cc], a, 0, 0, 0);
        acc[g][tt] = a;
      }
#pragma unroll
    for (int g = 0; g < 2; ++g)
#pragma unroll
      for (int r = 0; r < 4; ++r) {
        float zi = acc[g][0][r], zf = acc[g][1][r], zg = acc[g][2][r], zo = acc[g][3][r];
        float cn = sigmf(zf)*cst[g][r] + sigmf(zi)*ftanh(zg);
        float hn = sigmf(zo)*ftanh(cn);
        cst[g][r] = cn;
        int mr = r0 + r;
        if (uvalid) {
          hbuf[g][nxt][mr*128 + (((uu>>3) ^ (mr&7))<<3) + (uu&7)] = (_Float16)hn;
          dec[((size_t)(b0+g*16+mr)*SS + t)*HH + uu] = hn;
        }
      }
    __syncthreads();
  }
}

// ------------- out = dec @ oW^T + ob -------------
__global__ __launch_bounds__(256) void k_out(const float* __restrict__ dec,
    const float* __restrict__ oW, const float* __restrict__ ob, float* __restrict__ out0){
  __shared__ float oWt[100*64];
  __shared__ float dsr[64*100];
  int tid=threadIdx.x;
  size_t R0 = (size_t)blockIdx.x*64;
  for (int i=tid;i<6400;i+=256){ int j=i/100,k=i%100; oWt[k*64+j]=oW[i]; }
  for (int i=tid;i<6400;i+=256) dsr[i]=dec[R0*100 + i];
  __syncthreads();
  int j = tid&63, rb = tid>>6;
  float acc[16];
#pragma unroll
  for (int i=0;i<16;++i) acc[i]=0.f;
  for (int k=0;k<100;++k){
    float w = oWt[k*64+j];
#pragma unroll
    for (int i=0;i<16;++i) acc[i] += w*dsr[(rb + i*4)*100 + k];
  }
  float obv = ob[j];
#pragma unroll
  for (int i=0;i<16;++i) out0[(R0 + rb + i*4)*64 + j] = acc[i] + obv;
}

extern "C" void kernel_launch(void* const* d_in, const int* in_sizes, int n_in,
                              void* d_out, int out_size, void* d_ws, size_t ws_size,
                              hipStream_t stream) {
  const float* x    = (const float*)d_in[0];
  const float* c1w  = (const float*)d_in[1];
  const float* c1b  = (const float*)d_in[2];
  const float* c2w  = (const float*)d_in[3];
  const float* c2b  = (const float*)d_in[4];
  const float* fW1  = (const float*)d_in[5];
  const float* fb1  = (const float*)d_in[6];
  const float* fW2  = (const float*)d_in[7];
  const float* fb2  = (const float*)d_in[8];
  const float* cW1  = (const float*)d_in[9];
  const float* cb1  = (const float*)d_in[10];
  const float* cW2  = (const float*)d_in[11];
  const float* cb2  = (const float*)d_in[12];
  const float* eWih = (const float*)d_in[13];
  const float* eWhh = (const float*)d_in[14];
  const float* ebih = (const float*)d_in[15];
  const float* ebhh = (const float*)d_in[16];
  const float* aW1  = (const float*)d_in[17];
  const float* ab1  = (const float*)d_in[18];
  const float* aW2  = (const float*)d_in[19];
  const float* ab2  = (const float*)d_in[20];
  const float* bW   = (const float*)d_in[21];
  const float* bb   = (const float*)d_in[22];
  const float* h0W  = (const float*)d_in[23];
  const float* h0b  = (const float*)d_in[24];
  const float* c0W  = (const float*)d_in[25];
  const float* c0b  = (const float*)d_in[26];
  const float* dWih = (const float*)d_in[27];
  const float* dWhh = (const float*)d_in[28];
  const float* dbih = (const float*)d_in[29];
  const float* dbhh = (const float*)d_in[30];
  const float* oW   = (const float*)d_in[31];
  const float* ob   = (const float*)d_in[32];

  float* out0   = (float*)d_out;
  float* out_tw = out0 + (size_t)BB*SS*FF;
  float* out_fw = out_tw + (size_t)BB*SS;

  char* ws = (char*)d_ws;
  float*  gram   = (float*) (ws + 0);           // 16.78 MB
  __half* pool1  = (__half*)(ws + 16777216);    // 33.55 MB (channel-last [b][p][ic])
  float*  proc   = (float*) (ws + 50331648);    // 0.13 MB
  float*  fsbuf  = (float*) (ws + 50462720);    // 33.55 MB
  float*  wx     = (float*) (ws + 84017152);    // 33.55 MB
  float*  enc    = (float*) (ws + 117571584);   // 52.43 MB
  float*  dh0    = (float*) (ws + 170000384);   // 0.41 MB
  float*  dc0    = (float*) (ws + 170409984);   // 0.41 MB
  float*  decpre = (float*) (ws + 170819584);   // 1.64 MB
  float*  dec    = (float*) (ws + 172457984);   // 52.43 MB  (end ~224.9 MB)

  k_gram<<<BB, 256, 0, stream>>>(x, gram);
  k_conv1pool<<<BB, 256, 0, stream>>>(gram, c1w, c1b, pool1);
  k_conv2mfma<<<BB, 512, 0, stream>>>(pool1, c2w, c2b, proc);
  k_fs<<<2048, 256, 0, stream>>>(x, fW1, fb1, fW2, fb2, fsbuf);
  k_attnmlp<<<2048, 256, 0, stream>>>(x, fsbuf, proc, cW1, cb1, cW2, cb2, out_fw, wx);
  k_enc_mfma<<<32, 448, 0, stream>>>(wx, eWih, eWhh, ebih, ebhh, enc);
  k_attn<<<BB, 256, 0, stream>>>(enc, aW1, ab1, aW2, ab2, bW, bb, h0W, h0b, c0W, c0b,
                                 dWih, dbih, dbhh, out_tw, dh0, dc0, decpre);
  k_dec_mfma<<<32, 448, 0, stream>>>(decpre, dWhh, dh0, dc0, dec);
  k_out<<<2048, 256, 0, stream>>>(dec, oW, ob, out0);
}

// Round 6
// 1287.092 us; speedup vs baseline: 1.3454x; 1.3454x over previous
//
#include <hip/hip_runtime.h>
#include <hip/hip_fp16.h>

#define BB 1024
#define SS 128
#define FF 64
#define HH 100

typedef _Float16 h8 __attribute__((ext_vector_type(8)));
typedef _Float16 h4 __attribute__((ext_vector_type(4)));
typedef float f4v __attribute__((ext_vector_type(4)));

__device__ __forceinline__ float sigmf(float x){ return 1.0f/(1.0f+__expf(-x)); }
__device__ __forceinline__ float ftanh(float x){ float e=__expf(2.f*x); return 1.f - 2.f/(e+1.f); }

// LDS-only barrier: waits own LDS ops, does NOT drain vmcnt (global stores
// stay in flight across steps — removes the per-step store-drain stall).
#define LDS_BARRIER() __asm__ __volatile__("s_waitcnt lgkmcnt(0)\ns_barrier" ::: "memory")

__device__ __forceinline__ float wsum(float v){
#pragma unroll
  for (int m = 32; m >= 1; m >>= 1) v += __shfl_xor(v, m, 64);
  return v;
}
__device__ __forceinline__ float wmax(float v){
#pragma unroll
  for (int m = 32; m >= 1; m >>= 1) v = fmaxf(v, __shfl_xor(v, m, 64));
  return v;
}

// ---------------- gram: gram[b,i,j] = sum_s x[b,s,i]*x[b,s,j] ----------------
__global__ __launch_bounds__(256) void k_gram(const float* __restrict__ x, float* __restrict__ gram){
  __shared__ __align__(16) float xs[SS*FF];
  int b = blockIdx.x, tid = threadIdx.x;
  const float* xb = x + (size_t)b*SS*FF;
  for (int i = tid; i < SS*FF/4; i += 256)
    ((float4*)xs)[i] = ((const float4*)xb)[i];
  __syncthreads();
  int ti = (tid & 15) * 4, tj = (tid >> 4) * 4;
  float acc[4][4];
#pragma unroll
  for (int a=0;a<4;++a)
#pragma unroll
    for (int c=0;c<4;++c) acc[a][c]=0.f;
  for (int s = 0; s < SS; ++s) {
    const float* row = xs + s*FF;
    float4 av = *(const float4*)(row + ti);
    float4 bv = *(const float4*)(row + tj);
    float aa[4] = {av.x,av.y,av.z,av.w};
    float bb2[4] = {bv.x,bv.y,bv.z,bv.w};
#pragma unroll
    for (int a=0;a<4;++a)
#pragma unroll
      for (int c=0;c<4;++c) acc[a][c] += aa[a]*bb2[c];
  }
  float* g = gram + (size_t)b*4096;
#pragma unroll
  for (int a=0;a<4;++a)
#pragma unroll
    for (int c=0;c<4;++c) g[(ti+a)*64 + tj + c] = acc[a][c];
}

// ------- conv1(3x3,1->16,SAME)+bias+relu+maxpool2 -> half CHANNEL-LAST [B][p][ic] -------
__global__ __launch_bounds__(256) void k_conv1pool(const float* __restrict__ gram,
    const float* __restrict__ c1w, const float* __restrict__ c1b, __half* __restrict__ pool1){
  __shared__ float img2[66*66];
  __shared__ float ws1[144];
  __shared__ float bs1[16];
  int tid=threadIdx.x, b=blockIdx.x;
  for (int i=tid;i<66*66;i+=256) img2[i]=0.f;
  if (tid<144) ws1[tid]=c1w[tid];
  if (tid<16) bs1[tid]=c1b[tid];
  __syncthreads();
  const float* gb = gram + (size_t)b*4096;
  for (int i=tid;i<4096;i+=256){ int y=i>>6, xx=i&63; img2[(y+1)*66 + xx+1] = gb[i]; }
  __syncthreads();
  int oc = tid>>4, slot = tid&15;
  float wr[9];
#pragma unroll
  for (int t=0;t<9;++t) wr[t]=ws1[oc*9+t];
  float bo = bs1[oc];
  for (int p=slot;p<1024;p+=16){
    int py=p>>5, px=p&31;
    int y0=py*2, x0=px*2;
    float v[4][4];
#pragma unroll
    for (int wy=0;wy<4;++wy)
#pragma unroll
      for (int wxx=0;wxx<4;++wxx) v[wy][wxx]=img2[(y0+wy)*66 + x0+wxx];
    float s00=bo,s01=bo,s10=bo,s11=bo;
#pragma unroll
    for (int ky=0;ky<3;++ky)
#pragma unroll
      for (int kx=0;kx<3;++kx){
        float w=wr[ky*3+kx];
        s00 += v[ky][kx]*w;   s01 += v[ky][kx+1]*w;
        s10 += v[ky+1][kx]*w; s11 += v[ky+1][kx+1]*w;
      }
    float mx = fmaxf(fmaxf(s00,s01),fmaxf(s10,s11));
    pool1[(size_t)b*16384 + p*16 + oc] = __float2half(fmaxf(mx,0.f));
  }
}

// ================= conv2 as implicit-im2col MFMA GEMM =================
__global__ __launch_bounds__(512, 4) void k_conv2mfma(const __half* __restrict__ pool1,
    const float* __restrict__ c2w, const float* __restrict__ c2b, float* __restrict__ proc){
  __shared__ __align__(16) _Float16 img[(34*34+1)*24];   // +1 zero slot
  __shared__ float red[8][32];
  int b = blockIdx.x, tid = threadIdx.x;
  int wv = tid>>6, l = tid&63, lm = l&15, lq = l>>4;
  h8 bfr[2][5];
  float biasv[2];
#pragma unroll
  for (int nt=0; nt<2; ++nt){
    int oc = nt*16 + lm;
    biasv[nt] = c2b[oc];
#pragma unroll
    for (int c=0;c<5;++c){
      h8 f;
#pragma unroll
      for (int j=0;j<8;++j){
        int k = c*32 + lq*8 + j;
        int tap = k>>4, ic = k&15;
        f[j] = (_Float16)((tap<9) ? c2w[oc*144 + ic*9 + tap] : 0.f);
      }
      bfr[nt][c]=f;
    }
  }
  {
    h8 z = {0,0,0,0,0,0,0,0};
    for (int i=tid; i<(34*34+1)*3; i+=512) ((h8*)img)[i] = z;
  }
  __syncthreads();
  const __half* src = pool1 + (size_t)b*16384;
  for (int pp=tid; pp<1024; pp+=512){
    int y=pp>>5, x=pp&31;
    const h8* s = (const h8*)(src + pp*16);
    h8* d = (h8*)&img[((y+1)*34 + (x+1))*24];
    d[0]=s[0]; d[1]=s[1];
  }
  __syncthreads();
  f4v ssum0 = {0,0,0,0}, ssum1 = {0,0,0,0};
#pragma unroll 2
  for (int i=0;i<8;++i){
    int mt = wv + i*8;
    int y = mt>>1, x0 = (mt&1)*16;
    h8 afr[5];
#pragma unroll
    for (int c=0;c<5;++c){
      int tap = 2*c + (lq>>1);
      int addr;
      if (c==4 && lq>=2) addr = 34*34*24;
      else {
        int dy = tap/3 - 1, dx = tap - (tap/3)*3 - 1;
        addr = ((y+dy+1)*34 + (x0+lm+dx+1))*24 + (lq&1)*8;
      }
      afr[c] = *(const h8*)&img[addr];
    }
    f4v a0 = {biasv[0],biasv[0],biasv[0],biasv[0]};
    f4v a1 = {biasv[1],biasv[1],biasv[1],biasv[1]};
#pragma unroll
    for (int c=0;c<5;++c){
      a0 = __builtin_amdgcn_mfma_f32_16x16x32_f16(afr[c], bfr[0][c], a0, 0,0,0);
      a1 = __builtin_amdgcn_mfma_f32_16x16x32_f16(afr[c], bfr[1][c], a1, 0,0,0);
    }
#pragma unroll
    for (int r=0;r<4;++r){
      ssum0[r] += fmaxf(a0[r],0.f);
      ssum1[r] += fmaxf(a1[r],0.f);
    }
  }
  float s0 = ssum0[0]+ssum0[1]+ssum0[2]+ssum0[3];
  float s1 = ssum1[0]+ssum1[1]+ssum1[2]+ssum1[3];
  s0 += __shfl_xor(s0,16,64); s0 += __shfl_xor(s0,32,64);
  s1 += __shfl_xor(s1,16,64); s1 += __shfl_xor(s1,32,64);
  if (lq==0){ red[wv][lm]=s0; red[wv][16+lm]=s1; }
  __syncthreads();
  if (tid<32){
    float t=0.f;
#pragma unroll
    for (int w2=0;w2<8;++w2) t += red[w2][tid];
    proc[b*32+tid] = t*(1.f/1024.f);
  }
}

// ------------- fs = tanh(x@fW1^T+fb1)@fW2^T+fb2, per (b,s) row -------------
__global__ __launch_bounds__(256) void k_fs(const float* __restrict__ x,
    const float* __restrict__ fW1, const float* __restrict__ fb1,
    const float* __restrict__ fW2, const float* __restrict__ fb2,
    float* __restrict__ fs){
  __shared__ float w1t[64*32];
  __shared__ float w2t[32*64];
  __shared__ float b1s[32], b2s[64];
  __shared__ __align__(16) float xbuf[4][8][64];
  __shared__ float t1buf[4][8][32];
  int tid=threadIdx.x, wv=tid>>6, lane=tid&63;
  for (int i=tid;i<2048;i+=256){ int j=i>>6,k=i&63; w1t[k*32+j]=fW1[i]; }
  for (int i=tid;i<2048;i+=256){ int j=i>>5,k=i&31; w2t[k*64+j]=fW2[i]; }
  if (tid<32) b1s[tid]=fb1[tid];
  if (tid<64) b2s[tid]=fb2[tid];
  __syncthreads();
  size_t Rw = (size_t)blockIdx.x*64 + wv*16;
  int j = lane & 31, half = lane >> 5;
  for (int pass=0; pass<2; ++pass){
    size_t R0 = Rw + pass*8;
    const float4* src = (const float4*)(x + R0*64);
    float4* dst = (float4*)&xbuf[wv][0][0];
    for (int i=lane;i<128;i+=64) dst[i]=src[i];
    __syncthreads();
    {
      float a0=b1s[j],a1=b1s[j],a2=b1s[j],a3=b1s[j];
      const float* xr = &xbuf[wv][half*4][0];
      for (int k=0;k<64;++k){
        float w = w1t[k*32+j];
        a0 += w*xr[k]; a1 += w*xr[64+k]; a2 += w*xr[128+k]; a3 += w*xr[192+k];
      }
      float* t1r = &t1buf[wv][half*4][0];
      t1r[j]=ftanh(a0); t1r[32+j]=ftanh(a1); t1r[64+j]=ftanh(a2); t1r[96+j]=ftanh(a3);
    }
    __syncthreads();
    {
      float f[8];
#pragma unroll
      for (int r=0;r<8;++r) f[r]=b2s[lane];
      for (int k=0;k<32;++k){
        float w = w2t[k*64+lane];
#pragma unroll
        for (int r=0;r<8;++r) f[r] += w*t1buf[wv][r][k];
      }
#pragma unroll
      for (int r=0;r<8;++r) fs[(R0+r)*64 + lane] = f[r];
    }
    __syncthreads();
  }
}

// ------- aw = tanh([fs,proc]@cW1^T+cb1)@cW2^T+cb2; feature_w=softmax(aw); wx=x*fw -------
__global__ __launch_bounds__(256) void k_attnmlp(const float* __restrict__ x,
    const float* __restrict__ fs, const float* __restrict__ proc,
    const float* __restrict__ cW1, const float* __restrict__ cb1,
    const float* __restrict__ cW2, const float* __restrict__ cb2,
    float* __restrict__ fw_out, float* __restrict__ wx){
  __shared__ float c1t[96*64];
  __shared__ float c2t[64*64];
  __shared__ float cb1s[64], cb2s[64];
  __shared__ float cmb[4][4][96];
  __shared__ float h2b[4][4][64];
  int tid = threadIdx.x, wv = tid>>6, lane = tid&63;
  for (int i = tid; i < 6144; i += 256){ int j = i/96, k = i%96; c1t[k*64+j] = cW1[i]; }
  for (int i = tid; i < 4096; i += 256){ int j = i>>6, k = i&63; c2t[k*64+j] = cW2[i]; }
  if (tid < 64) { cb1s[tid] = cb1[tid]; cb2s[tid] = cb2[tid]; }
  __syncthreads();
  size_t Rw = (size_t)blockIdx.x*64 + wv*16;
  for (int pass = 0; pass < 4; ++pass) {
    size_t R0 = Rw + pass*4;
    for (int i = lane; i < 384; i += 64) {
      int r = i/96, k = i%96;
      size_t R = R0 + r;
      cmb[wv][r][k] = (k < 64) ? fs[R*64 + k] : proc[(R>>7)*32 + (k-64)];
    }
    __syncthreads();
    float h0a=cb1s[lane],h1a=cb1s[lane],h2a=cb1s[lane],h3a=cb1s[lane];
    for (int k = 0; k < 96; ++k) {
      float w = c1t[k*64+lane];
      h0a += w*cmb[wv][0][k]; h1a += w*cmb[wv][1][k];
      h2a += w*cmb[wv][2][k]; h3a += w*cmb[wv][3][k];
    }
    h2b[wv][0][lane]=ftanh(h0a); h2b[wv][1][lane]=ftanh(h1a);
    h2b[wv][2][lane]=ftanh(h2a); h2b[wv][3][lane]=ftanh(h3a);
    __syncthreads();
    float a0=cb2s[lane],a1=cb2s[lane],a2=cb2s[lane],a3=cb2s[lane];
    for (int k = 0; k < 64; ++k) {
      float w = c2t[k*64+lane];
      a0 += w*h2b[wv][0][k]; a1 += w*h2b[wv][1][k];
      a2 += w*h2b[wv][2][k]; a3 += w*h2b[wv][3][k];
    }
    float m0=wmax(a0), m1=wmax(a1), m2=wmax(a2), m3=wmax(a3);
    float e0=__expf(a0-m0), e1=__expf(a1-m1), e2=__expf(a2-m2), e3=__expf(a3-m3);
    float s0=wsum(e0), s1=wsum(e1), s2=wsum(e2), s3=wsum(e3);
    float f0v=e0/s0, f1v=e1/s1, f2v=e2/s2, f3v=e3/s3;
    size_t R;
    R=R0+0; fw_out[R*64+lane]=f0v; wx[R*64+lane]=x[R*64+lane]*f0v;
    R=R0+1; fw_out[R*64+lane]=f1v; wx[R*64+lane]=x[R*64+lane]*f1v;
    R=R0+2; fw_out[R*64+lane]=f2v; wx[R*64+lane]=x[R*64+lane]*f2v;
    R=R0+3; fw_out[R*64+lane]=f3v; wx[R*64+lane]=x[R*64+lane]*f3v;
    __syncthreads();
  }
}

// ================= MFMA encoder LSTM (swapped operands) =================
// 64 blocks x 448 thr. A = weights (VGPR-resident), B = activations from LDS.
// D: col=lane&15 = batch row, row=quad*4+r = unit -> each lane owns 4
// CONTIGUOUS units for one batch row: h-writeback = 1 ds_write_b64, enc
// store = 1 dwordx4 (was 4x ds_write_b16 + 4 scattered dwords).
// In-loop barrier = lgkmcnt-only (global stores never drained per step).
// Anti-NaN: hbuf (both phases) zeroed; units >=100 never written.
__global__ __launch_bounds__(448, 2) void k_enc_mfma(const float* __restrict__ wx,
    const float* __restrict__ Wih, const float* __restrict__ Whh,
    const float* __restrict__ bih, const float* __restrict__ bhh,
    float* __restrict__ enc){
  __shared__ __align__(16) _Float16 hbuf[2][16*128];
  __shared__ __align__(16) _Float16 xst[2][16*64];
  int tid = threadIdx.x;
  int w = tid >> 6, l = tid & 63;
  int lm = l & 15, lq = l >> 4;
  int b0 = blockIdx.x * 16;
  int au = w*16 + lm;              // A-side (weight-row) unit for this lane
  bool avalid = au < 100;
  int u0 = w*16 + lq*4;            // output units u0..u0+3 (D rows)
  bool uvalid = (u0 + 3) < 100;
  // ---- weight A-fragments: A[m=lm][k=lq*8+j] ----
  h8 wfr[4][6];
#pragma unroll
  for (int tt=0; tt<4; ++tt){
    int row = tt*100 + au;
#pragma unroll
    for (int cc=0; cc<6; ++cc){
      h8 f;
#pragma unroll
      for (int j=0;j<8;++j){
        int kg = cc*32 + lq*8 + j;
        float v = 0.f;
        if (avalid){
          if (kg < 64) v = Wih[(size_t)row*64 + kg];
          else { int kh = kg - 64; if (kh < 100) v = Whh[(size_t)row*100 + kh]; }
        }
        f[j] = (_Float16)v;
      }
      wfr[tt][cc] = f;
    }
  }
  // ---- bias per output unit (C-init rows) ----
  f4v biasv[4];
#pragma unroll
  for (int tt=0; tt<4; ++tt){
    if (uvalid){
      float4 bi = *(const float4*)&bih[tt*100 + u0];
      float4 bh = *(const float4*)&bhh[tt*100 + u0];
      f4v bv2 = {bi.x+bh.x, bi.y+bh.y, bi.z+bh.z, bi.w+bh.w};
      biasv[tt] = bv2;
    } else { f4v z = {0,0,0,0}; biasv[tt] = z; }
  }
  // zero BOTH hbuf phases
  for (int i = tid; i < 2*16*128; i += 448) hbuf[0][i] = (_Float16)0.f;
  // stage x_0 (threads 0..255)
  int sm = tid >> 4, skq = tid & 15;
  if (tid < 256){
    float4 xv0 = *(const float4*)(wx + ((size_t)(b0+sm)*SS + 0)*FF + skq*4);
    h4 p = {(_Float16)xv0.x,(_Float16)xv0.y,(_Float16)xv0.z,(_Float16)xv0.w};
    *(h4*)&xst[0][sm*64 + (((skq>>1) ^ (sm&7))<<3) + (skq&1)*4] = p;
  }
  float cst[4] = {0.f,0.f,0.f,0.f};
  // fixed h-writeback address: row lm, units u0..u0+3 (block = 2w+(lq>>1))
  int hwaddr = lm*128 + (((2*w + (lq>>1)) ^ (lm&7))<<3) + (lq&1)*4;
  __syncthreads();
  for (int t = 0; t < SS; ++t){
    int cur = t & 1, nxt = cur ^ 1;
    float4 xv;
    bool doPref = (tid < 256) && (t < SS-1);
    if (doPref) xv = *(const float4*)(wx + ((size_t)(b0+sm)*SS + (t+1))*FF + skq*4);
    // B-fragments (activations): B[k=lq*8+j][n=lm]
    h8 bact[6];
#pragma unroll
    for (int cc=0; cc<2; ++cc)
      bact[cc] = *(const h8*)&xst[cur][lm*64 + (((cc*4+lq) ^ (lm&7))<<3)];
#pragma unroll
    for (int cc=0; cc<4; ++cc)
      bact[2+cc] = *(const h8*)&hbuf[cur][lm*128 + (((cc*4+lq) ^ (lm&7))<<3)];
    f4v acc[4];
#pragma unroll
    for (int tt=0; tt<4; ++tt){
      f4v a = biasv[tt];
#pragma unroll
      for (int cc=0; cc<6; ++cc)
        a = __builtin_amdgcn_mfma_f32_16x16x32_f16(wfr[tt][cc], bact[cc], a, 0, 0, 0);
      acc[tt] = a;
    }
    float hn[4];
#pragma unroll
    for (int r=0;r<4;++r){
      float cn = sigmf(acc[1][r])*cst[r] + sigmf(acc[0][r])*ftanh(acc[2][r]);
      hn[r] = sigmf(acc[3][r])*ftanh(cn);
      cst[r] = cn;
    }
    if (uvalid){
      h4 hp = {(_Float16)hn[0],(_Float16)hn[1],(_Float16)hn[2],(_Float16)hn[3]};
      *(h4*)&hbuf[nxt][hwaddr] = hp;
      float4 st; st.x=hn[0]; st.y=hn[1]; st.z=hn[2]; st.w=hn[3];
      *(float4*)&enc[((size_t)(b0+lm)*SS + t)*HH + u0] = st;
    }
    if (doPref){
      h4 p = {(_Float16)xv.x,(_Float16)xv.y,(_Float16)xv.z,(_Float16)xv.w};
      *(h4*)&xst[nxt][sm*64 + (((skq>>1) ^ (sm&7))<<3) + (skq&1)*4] = p;
    }
    LDS_BARRIER();
  }
}

// ------- ts/time_w softmax over S, ctx, bott, dh0, dc0, decpre; one block per batch -------
__global__ __launch_bounds__(256) void k_attn(const float* __restrict__ enc,
    const float* __restrict__ aW1, const float* __restrict__ ab1,
    const float* __restrict__ aW2, const float* __restrict__ ab2,
    const float* __restrict__ bW, const float* __restrict__ bb_,
    const float* __restrict__ h0W, const float* __restrict__ h0b,
    const float* __restrict__ c0W, const float* __restrict__ c0b,
    const float* __restrict__ dWih, const float* __restrict__ dbih, const float* __restrict__ dbhh,
    float* __restrict__ tw_out, float* __restrict__ dh0, float* __restrict__ dc0,
    float* __restrict__ decpre){
  __shared__ float a1t[100*64];
  __shared__ float a2s[64], ab1s[64];
  __shared__ float tsb[SS];
  __shared__ float ctxb[HH];
  __shared__ float bottb[32];
  __shared__ float red[8];
  int tid = threadIdx.x, wv = tid>>6, lane = tid&63;
  int b = blockIdx.x;
  const float* encb = enc + (size_t)b*SS*HH;
  for (int i=tid;i<6400;i+=256){ int jj=i/100,k=i%100; a1t[k*64+jj]=aW1[i]; }
  if (tid<64){ a2s[tid]=aW2[tid]; ab1s[tid]=ab1[tid]; }
  __syncthreads();
  float ab2v = ab2[0];
  for (int si=0; si<32; ++si){
    int s = wv*32+si;
    const float4* er = (const float4*)(encb + s*HH);
    float a = ab1s[lane];
#pragma unroll
    for (int kc=0;kc<25;++kc){
      float4 e = er[kc];
      a += e.x*a1t[(kc*4+0)*64+lane] + e.y*a1t[(kc*4+1)*64+lane]
         + e.z*a1t[(kc*4+2)*64+lane] + e.w*a1t[(kc*4+3)*64+lane];
    }
    float contrib = a2s[lane]*ftanh(a);
    float t = wsum(contrib);
    if (lane==0) tsb[s] = t + ab2v;
  }
  __syncthreads();
  float tv = (tid < SS) ? tsb[tid] : -1e30f;
  float m = wmax(tv);
  if (lane==0) red[wv]=m;
  __syncthreads();
  m = fmaxf(fmaxf(red[0],red[1]), fmaxf(red[2],red[3]));
  float e = (tid < SS) ? __expf(tv - m) : 0.f;
  float sm = wsum(e);
  if (lane==0) red[4+wv]=sm;
  __syncthreads();
  float denom = red[4]+red[5]+red[6]+red[7];
  if (tid < SS){
    float twv = e/denom;
    tw_out[(size_t)b*SS + tid] = twv;
    tsb[tid] = twv;
  }
  __syncthreads();
  if (tid < HH){
    float a = 0.f;
    for (int s=0;s<SS;++s) a += tsb[s]*encb[s*HH + tid];
    ctxb[tid]=a;
  }
  __syncthreads();
  if (tid < 32){
    float a = bb_[tid];
    const float* wr = bW + tid*HH;
    for (int k=0;k<HH;++k) a += wr[k]*ctxb[k];
    bottb[tid]=a;
  }
  __syncthreads();
  if (tid < HH){
    float a = h0b[tid];
    const float* wr = h0W + tid*32;
#pragma unroll
    for (int k=0;k<32;++k) a += wr[k]*bottb[k];
    dh0[(size_t)b*HH + tid] = a;
  } else if (tid < 200){
    int jj = tid-100;
    float a = c0b[jj];
    const float* wr = c0W + jj*32;
#pragma unroll
    for (int k=0;k<32;++k) a += wr[k]*bottb[k];
    dc0[(size_t)b*HH + jj] = a;
  }
  {
    int jj = tid;
    float a = dbih[jj]+dbhh[jj];
    const float* wr = dWih + jj*32;
#pragma unroll
    for (int k=0;k<32;++k) a += wr[k]*bottb[k];
    decpre[(size_t)b*400 + jj] = a;
    jj = tid + 256;
    if (jj < 400){
      float a2v = dbih[jj]+dbhh[jj];
      const float* wr2 = dWih + jj*32;
#pragma unroll
      for (int k=0;k<32;++k) a2v += wr2[k]*bottb[k];
      decpre[(size_t)b*400 + jj] = a2v;
    }
  }
}

// ================= MFMA decoder LSTM (swapped operands) =================
__global__ __launch_bounds__(448, 2) void k_dec_mfma(const float* __restrict__ decpre,
    const float* __restrict__ Whh,
    const float* __restrict__ dh0, const float* __restrict__ dc0,
    float* __restrict__ dec){
  __shared__ __align__(16) _Float16 hbuf[2][16*128];
  int tid = threadIdx.x;
  int w = tid >> 6, l = tid & 63;
  int lm = l & 15, lq = l >> 4;
  int b0 = blockIdx.x * 16;
  int au = w*16 + lm;
  bool avalid = au < 100;
  int u0 = w*16 + lq*4;
  bool uvalid = (u0 + 3) < 100;
  h8 wfr[4][4];
#pragma unroll
  for (int tt = 0; tt < 4; ++tt){
    int row = tt*100 + au;
#pragma unroll
    for (int cc = 0; cc < 4; ++cc){
      h8 f;
#pragma unroll
      for (int j = 0; j < 8; ++j){
        int kh = cc*32 + lq*8 + j;
        float v = (avalid && kh < 100) ? Whh[(size_t)row*100 + kh] : 0.f;
        f[j] = (_Float16)v;
      }
      wfr[tt][cc] = f;
    }
  }
  // pre-accumulator (decpre = dWih@bott + biases) and c-state, vector loads
  f4v pre[4];
  float cst[4] = {0.f,0.f,0.f,0.f};
  if (uvalid){
#pragma unroll
    for (int tt = 0; tt < 4; ++tt){
      float4 p = *(const float4*)&decpre[(size_t)(b0+lm)*400 + tt*100 + u0];
      f4v pv = {p.x, p.y, p.z, p.w};
      pre[tt] = pv;
    }
    float4 c4 = *(const float4*)&dc0[(size_t)(b0+lm)*100 + u0];
    cst[0]=c4.x; cst[1]=c4.y; cst[2]=c4.z; cst[3]=c4.w;
  } else {
    f4v z = {0,0,0,0};
#pragma unroll
    for (int tt = 0; tt < 4; ++tt) pre[tt] = z;
  }
  // zero phase 1; fill phase 0 from dh0 (units >=100 zero)
  for (int i = tid; i < 16*128; i += 448) hbuf[1][i] = (_Float16)0.f;
  for (int idx = tid; idx < 16*128; idx += 448){
    int m = idx >> 7, u2 = idx & 127;
    float v = (u2 < 100) ? dh0[(size_t)(b0+m)*HH + u2] : 0.f;
    hbuf[0][m*128 + (((u2>>3) ^ (m&7))<<3) + (u2&7)] = (_Float16)v;
  }
  int hwaddr = lm*128 + (((2*w + (lq>>1)) ^ (lm&7))<<3) + (lq&1)*4;
  __syncthreads();
  for (int t = 0; t < SS; ++t){
    int cur = t & 1, nxt = cur ^ 1;
    h8 bact[4];
#pragma unroll
    for (int cc = 0; cc < 4; ++cc)
      bact[cc] = *(const h8*)&hbuf[cur][lm*128 + (((cc*4+lq) ^ (lm&7))<<3)];
    f4v acc[4];
#pragma unroll
    for (int tt = 0; tt < 4; ++tt){
      f4v a = pre[tt];
#pragma unroll
      for (int cc = 0; cc < 4; ++cc)
        a = __builtin_amdgcn_mfma_f32_16x16x32_f16(wfr[tt][cc], bact[cc], a, 0, 0, 0);
      acc[tt] = a;
    }
    float hn[4];
#pragma unroll
    for (int r=0;r<4;++r){
      float cn = sigmf(acc[1][r])*cst[r] + sigmf(acc[0][r])*ftanh(acc[2][r]);
      hn[r] = sigmf(acc[3][r])*ftanh(cn);
      cst[r] = cn;
    }
    if (uvalid){
      h4 hp = {(_Float16)hn[0],(_Float16)hn[1],(_Float16)hn[2],(_Float16)hn[3]};
      *(h4*)&hbuf[nxt][hwaddr] = hp;
      float4 st; st.x=hn[0]; st.y=hn[1]; st.z=hn[2]; st.w=hn[3];
      *(float4*)&dec[((size_t)(b0+lm)*SS + t)*HH + u0] = st;
    }
    LDS_BARRIER();
  }
}

// ------------- out = dec @ oW^T + ob -------------
__global__ __launch_bounds__(256) void k_out(const float* __restrict__ dec,
    const float* __restrict__ oW, const float* __restrict__ ob, float* __restrict__ out0){
  __shared__ float oWt[100*64];
  __shared__ float dsr[64*100];
  int tid=threadIdx.x;
  size_t R0 = (size_t)blockIdx.x*64;
  for (int i=tid;i<6400;i+=256){ int j=i/100,k=i%100; oWt[k*64+j]=oW[i]; }
  for (int i=tid;i<6400;i+=256) dsr[i]=dec[R0*100 + i];
  __syncthreads();
  int j = tid&63, rb = tid>>6;
  float acc[16];
#pragma unroll
  for (int i=0;i<16;++i) acc[i]=0.f;
  for (int k=0;k<100;++k){
    float w = oWt[k*64+j];
#pragma unroll
    for (int i=0;i<16;++i) acc[i] += w*dsr[(rb + i*4)*100 + k];
  }
  float obv = ob[j];
#pragma unroll
  for (int i=0;i<16;++i) out0[(R0 + rb + i*4)*64 + j] = acc[i] + obv;
}

extern "C" void kernel_launch(void* const* d_in, const int* in_sizes, int n_in,
                              void* d_out, int out_size, void* d_ws, size_t ws_size,
                              hipStream_t stream) {
  const float* x    = (const float*)d_in[0];
  const float* c1w  = (const float*)d_in[1];
  const float* c1b  = (const float*)d_in[2];
  const float* c2w  = (const float*)d_in[3];
  const float* c2b  = (const float*)d_in[4];
  const float* fW1  = (const float*)d_in[5];
  const float* fb1  = (const float*)d_in[6];
  const float* fW2  = (const float*)d_in[7];
  const float* fb2  = (const float*)d_in[8];
  const float* cW1  = (const float*)d_in[9];
  const float* cb1  = (const float*)d_in[10];
  const float* cW2  = (const float*)d_in[11];
  const float* cb2  = (const float*)d_in[12];
  const float* eWih = (const float*)d_in[13];
  const float* eWhh = (const float*)d_in[14];
  const float* ebih = (const float*)d_in[15];
  const float* ebhh = (const float*)d_in[16];
  const float* aW1  = (const float*)d_in[17];
  const float* ab1  = (const float*)d_in[18];
  const float* aW2  = (const float*)d_in[19];
  const float* ab2  = (const float*)d_in[20];
  const float* bW   = (const float*)d_in[21];
  const float* bb   = (const float*)d_in[22];
  const float* h0W  = (const float*)d_in[23];
  const float* h0b  = (const float*)d_in[24];
  const float* c0W  = (const float*)d_in[25];
  const float* c0b  = (const float*)d_in[26];
  const float* dWih = (const float*)d_in[27];
  const float* dWhh = (const float*)d_in[28];
  const float* dbih = (const float*)d_in[29];
  const float* dbhh = (const float*)d_in[30];
  const float* oW   = (const float*)d_in[31];
  const float* ob   = (const float*)d_in[32];

  float* out0   = (float*)d_out;
  float* out_tw = out0 + (size_t)BB*SS*FF;
  float* out_fw = out_tw + (size_t)BB*SS;

  char* ws = (char*)d_ws;
  float*  gram   = (float*) (ws + 0);           // 16.78 MB
  __half* pool1  = (__half*)(ws + 16777216);    // 33.55 MB (channel-last [b][p][ic])
  float*  proc   = (float*) (ws + 50331648);    // 0.13 MB
  float*  fsbuf  = (float*) (ws + 50462720);    // 33.55 MB
  float*  wx     = (float*) (ws + 84017152);    // 33.55 MB
  float*  enc    = (float*) (ws + 117571584);   // 52.43 MB
  float*  dh0    = (float*) (ws + 170000384);   // 0.41 MB
  float*  dc0    = (float*) (ws + 170409984);   // 0.41 MB
  float*  decpre = (float*) (ws + 170819584);   // 1.64 MB
  float*  dec    = (float*) (ws + 172457984);   // 52.43 MB  (end ~224.9 MB)

  k_gram<<<BB, 256, 0, stream>>>(x, gram);
  k_conv1pool<<<BB, 256, 0, stream>>>(gram, c1w, c1b, pool1);
  k_conv2mfma<<<BB, 512, 0, stream>>>(pool1, c2w, c2b, proc);
  k_fs<<<2048, 256, 0, stream>>>(x, fW1, fb1, fW2, fb2, fsbuf);
  k_attnmlp<<<2048, 256, 0, stream>>>(x, fsbuf, proc, cW1, cb1, cW2, cb2, out_fw, wx);
  k_enc_mfma<<<64, 448, 0, stream>>>(wx, eWih, eWhh, ebih, ebhh, enc);
  k_attn<<<BB, 256, 0, stream>>>(enc, aW1, ab1, aW2, ab2, bW, bb, h0W, h0b, c0W, c0b,
                                 dWih, dbih, dbhh, out_tw, dh0, dc0, decpre);
  k_dec_mfma<<<64, 448, 0, stream>>>(decpre, dWhh, dh0, dc0, dec);
  k_out<<<2048, 256, 0, stream>>>(dec, oW, ob, out0);
}

// Round 7
// 1000.412 us; speedup vs baseline: 1.7309x; 1.2866x over previous
//
#include <hip/hip_runtime.h>
#include <hip/hip_fp16.h>

#define BB 1024
#define SS 128
#define FF 64
#define HH 100

typedef _Float16 h8 __attribute__((ext_vector_type(8)));
typedef _Float16 h4 __attribute__((ext_vector_type(4)));
typedef float f4v __attribute__((ext_vector_type(4)));

__device__ __forceinline__ float sigmf(float x){ return 1.0f/(1.0f+__expf(-x)); }
__device__ __forceinline__ float ftanh(float x){ float e=__expf(2.f*x); return 1.f - 2.f/(e+1.f); }

// LDS-only barrier: waits own LDS ops, does NOT drain vmcnt (global stores
// stay in flight across steps).
#define LDS_BARRIER() __asm__ __volatile__("s_waitcnt lgkmcnt(0)\ns_barrier" ::: "memory")

__device__ __forceinline__ float wsum(float v){
#pragma unroll
  for (int m = 32; m >= 1; m >>= 1) v += __shfl_xor(v, m, 64);
  return v;
}
__device__ __forceinline__ float wmax(float v){
#pragma unroll
  for (int m = 32; m >= 1; m >>= 1) v = fmaxf(v, __shfl_xor(v, m, 64));
  return v;
}

// ---------------- gram: gram[b,i,j] = sum_s x[b,s,i]*x[b,s,j] ----------------
__global__ __launch_bounds__(256) void k_gram(const float* __restrict__ x, float* __restrict__ gram){
  __shared__ __align__(16) float xs[SS*FF];
  int b = blockIdx.x, tid = threadIdx.x;
  const float* xb = x + (size_t)b*SS*FF;
  for (int i = tid; i < SS*FF/4; i += 256)
    ((float4*)xs)[i] = ((const float4*)xb)[i];
  __syncthreads();
  int ti = (tid & 15) * 4, tj = (tid >> 4) * 4;
  float acc[4][4];
#pragma unroll
  for (int a=0;a<4;++a)
#pragma unroll
    for (int c=0;c<4;++c) acc[a][c]=0.f;
  for (int s = 0; s < SS; ++s) {
    const float* row = xs + s*FF;
    float4 av = *(const float4*)(row + ti);
    float4 bv = *(const float4*)(row + tj);
    float aa[4] = {av.x,av.y,av.z,av.w};
    float bb2[4] = {bv.x,bv.y,bv.z,bv.w};
#pragma unroll
    for (int a=0;a<4;++a)
#pragma unroll
      for (int c=0;c<4;++c) acc[a][c] += aa[a]*bb2[c];
  }
  float* g = gram + (size_t)b*4096;
#pragma unroll
  for (int a=0;a<4;++a)
#pragma unroll
    for (int c=0;c<4;++c) g[(ti+a)*64 + tj + c] = acc[a][c];
}

// ------- conv1(3x3,1->16,SAME)+bias+relu+maxpool2 -> half CHANNEL-LAST [B][p][ic] -------
__global__ __launch_bounds__(256) void k_conv1pool(const float* __restrict__ gram,
    const float* __restrict__ c1w, const float* __restrict__ c1b, __half* __restrict__ pool1){
  __shared__ float img2[66*66];
  __shared__ float ws1[144];
  __shared__ float bs1[16];
  int tid=threadIdx.x, b=blockIdx.x;
  for (int i=tid;i<66*66;i+=256) img2[i]=0.f;
  if (tid<144) ws1[tid]=c1w[tid];
  if (tid<16) bs1[tid]=c1b[tid];
  __syncthreads();
  const float* gb = gram + (size_t)b*4096;
  for (int i=tid;i<4096;i+=256){ int y=i>>6, xx=i&63; img2[(y+1)*66 + xx+1] = gb[i]; }
  __syncthreads();
  int oc = tid>>4, slot = tid&15;
  float wr[9];
#pragma unroll
  for (int t=0;t<9;++t) wr[t]=ws1[oc*9+t];
  float bo = bs1[oc];
  for (int p=slot;p<1024;p+=16){
    int py=p>>5, px=p&31;
    int y0=py*2, x0=px*2;
    float v[4][4];
#pragma unroll
    for (int wy=0;wy<4;++wy)
#pragma unroll
      for (int wxx=0;wxx<4;++wxx) v[wy][wxx]=img2[(y0+wy)*66 + x0+wxx];
    float s00=bo,s01=bo,s10=bo,s11=bo;
#pragma unroll
    for (int ky=0;ky<3;++ky)
#pragma unroll
      for (int kx=0;kx<3;++kx){
        float w=wr[ky*3+kx];
        s00 += v[ky][kx]*w;   s01 += v[ky][kx+1]*w;
        s10 += v[ky+1][kx]*w; s11 += v[ky+1][kx+1]*w;
      }
    float mx = fmaxf(fmaxf(s00,s01),fmaxf(s10,s11));
    pool1[(size_t)b*16384 + p*16 + oc] = __float2half(fmaxf(mx,0.f));
  }
}

// ================= conv2 as implicit-im2col MFMA GEMM =================
__global__ __launch_bounds__(512, 4) void k_conv2mfma(const __half* __restrict__ pool1,
    const float* __restrict__ c2w, const float* __restrict__ c2b, float* __restrict__ proc){
  __shared__ __align__(16) _Float16 img[(34*34+1)*24];   // +1 zero slot
  __shared__ float red[8][32];
  int b = blockIdx.x, tid = threadIdx.x;
  int wv = tid>>6, l = tid&63, lm = l&15, lq = l>>4;
  h8 bfr[2][5];
  float biasv[2];
#pragma unroll
  for (int nt=0; nt<2; ++nt){
    int oc = nt*16 + lm;
    biasv[nt] = c2b[oc];
#pragma unroll
    for (int c=0;c<5;++c){
      h8 f;
#pragma unroll
      for (int j=0;j<8;++j){
        int k = c*32 + lq*8 + j;
        int tap = k>>4, ic = k&15;
        f[j] = (_Float16)((tap<9) ? c2w[oc*144 + ic*9 + tap] : 0.f);
      }
      bfr[nt][c]=f;
    }
  }
  {
    h8 z = {0,0,0,0,0,0,0,0};
    for (int i=tid; i<(34*34+1)*3; i+=512) ((h8*)img)[i] = z;
  }
  __syncthreads();
  const __half* src = pool1 + (size_t)b*16384;
  for (int pp=tid; pp<1024; pp+=512){
    int y=pp>>5, x=pp&31;
    const h8* s = (const h8*)(src + pp*16);
    h8* d = (h8*)&img[((y+1)*34 + (x+1))*24];
    d[0]=s[0]; d[1]=s[1];
  }
  __syncthreads();
  f4v ssum0 = {0,0,0,0}, ssum1 = {0,0,0,0};
#pragma unroll 2
  for (int i=0;i<8;++i){
    int mt = wv + i*8;
    int y = mt>>1, x0 = (mt&1)*16;
    h8 afr[5];
#pragma unroll
    for (int c=0;c<5;++c){
      int tap = 2*c + (lq>>1);
      int addr;
      if (c==4 && lq>=2) addr = 34*34*24;
      else {
        int dy = tap/3 - 1, dx = tap - (tap/3)*3 - 1;
        addr = ((y+dy+1)*34 + (x0+lm+dx+1))*24 + (lq&1)*8;
      }
      afr[c] = *(const h8*)&img[addr];
    }
    f4v a0 = {biasv[0],biasv[0],biasv[0],biasv[0]};
    f4v a1 = {biasv[1],biasv[1],biasv[1],biasv[1]};
#pragma unroll
    for (int c=0;c<5;++c){
      a0 = __builtin_amdgcn_mfma_f32_16x16x32_f16(afr[c], bfr[0][c], a0, 0,0,0);
      a1 = __builtin_amdgcn_mfma_f32_16x16x32_f16(afr[c], bfr[1][c], a1, 0,0,0);
    }
#pragma unroll
    for (int r=0;r<4;++r){
      ssum0[r] += fmaxf(a0[r],0.f);
      ssum1[r] += fmaxf(a1[r],0.f);
    }
  }
  float s0 = ssum0[0]+ssum0[1]+ssum0[2]+ssum0[3];
  float s1 = ssum1[0]+ssum1[1]+ssum1[2]+ssum1[3];
  s0 += __shfl_xor(s0,16,64); s0 += __shfl_xor(s0,32,64);
  s1 += __shfl_xor(s1,16,64); s1 += __shfl_xor(s1,32,64);
  if (lq==0){ red[wv][lm]=s0; red[wv][16+lm]=s1; }
  __syncthreads();
  if (tid<32){
    float t=0.f;
#pragma unroll
    for (int w2=0;w2<8;++w2) t += red[w2][tid];
    proc[b*32+tid] = t*(1.f/1024.f);
  }
}

// ------------- fs = tanh(x@fW1^T+fb1)@fW2^T+fb2, per (b,s) row -------------
__global__ __launch_bounds__(256) void k_fs(const float* __restrict__ x,
    const float* __restrict__ fW1, const float* __restrict__ fb1,
    const float* __restrict__ fW2, const float* __restrict__ fb2,
    float* __restrict__ fs){
  __shared__ float w1t[64*32];
  __shared__ float w2t[32*64];
  __shared__ float b1s[32], b2s[64];
  __shared__ __align__(16) float xbuf[4][8][64];
  __shared__ float t1buf[4][8][32];
  int tid=threadIdx.x, wv=tid>>6, lane=tid&63;
  for (int i=tid;i<2048;i+=256){ int j=i>>6,k=i&63; w1t[k*32+j]=fW1[i]; }
  for (int i=tid;i<2048;i+=256){ int j=i>>5,k=i&31; w2t[k*64+j]=fW2[i]; }
  if (tid<32) b1s[tid]=fb1[tid];
  if (tid<64) b2s[tid]=fb2[tid];
  __syncthreads();
  size_t Rw = (size_t)blockIdx.x*64 + wv*16;
  int j = lane & 31, half = lane >> 5;
  for (int pass=0; pass<2; ++pass){
    size_t R0 = Rw + pass*8;
    const float4* src = (const float4*)(x + R0*64);
    float4* dst = (float4*)&xbuf[wv][0][0];
    for (int i=lane;i<128;i+=64) dst[i]=src[i];
    __syncthreads();
    {
      float a0=b1s[j],a1=b1s[j],a2=b1s[j],a3=b1s[j];
      const float* xr = &xbuf[wv][half*4][0];
      for (int k=0;k<64;++k){
        float w = w1t[k*32+j];
        a0 += w*xr[k]; a1 += w*xr[64+k]; a2 += w*xr[128+k]; a3 += w*xr[192+k];
      }
      float* t1r = &t1buf[wv][half*4][0];
      t1r[j]=ftanh(a0); t1r[32+j]=ftanh(a1); t1r[64+j]=ftanh(a2); t1r[96+j]=ftanh(a3);
    }
    __syncthreads();
    {
      float f[8];
#pragma unroll
      for (int r=0;r<8;++r) f[r]=b2s[lane];
      for (int k=0;k<32;++k){
        float w = w2t[k*64+lane];
#pragma unroll
        for (int r=0;r<8;++r) f[r] += w*t1buf[wv][r][k];
      }
#pragma unroll
      for (int r=0;r<8;++r) fs[(R0+r)*64 + lane] = f[r];
    }
    __syncthreads();
  }
}

// ------- aw = tanh([fs,proc]@cW1^T+cb1)@cW2^T+cb2; feature_w=softmax(aw); wx=x*fw -------
__global__ __launch_bounds__(256) void k_attnmlp(const float* __restrict__ x,
    const float* __restrict__ fs, const float* __restrict__ proc,
    const float* __restrict__ cW1, const float* __restrict__ cb1,
    const float* __restrict__ cW2, const float* __restrict__ cb2,
    float* __restrict__ fw_out, float* __restrict__ wx){
  __shared__ float c1t[96*64];
  __shared__ float c2t[64*64];
  __shared__ float cb1s[64], cb2s[64];
  __shared__ float cmb[4][4][96];
  __shared__ float h2b[4][4][64];
  int tid = threadIdx.x, wv = tid>>6, lane = tid&63;
  for (int i = tid; i < 6144; i += 256){ int j = i/96, k = i%96; c1t[k*64+j] = cW1[i]; }
  for (int i = tid; i < 4096; i += 256){ int j = i>>6, k = i&63; c2t[k*64+j] = cW2[i]; }
  if (tid < 64) { cb1s[tid] = cb1[tid]; cb2s[tid] = cb2[tid]; }
  __syncthreads();
  size_t Rw = (size_t)blockIdx.x*64 + wv*16;
  for (int pass = 0; pass < 4; ++pass) {
    size_t R0 = Rw + pass*4;
    for (int i = lane; i < 384; i += 64) {
      int r = i/96, k = i%96;
      size_t R = R0 + r;
      cmb[wv][r][k] = (k < 64) ? fs[R*64 + k] : proc[(R>>7)*32 + (k-64)];
    }
    __syncthreads();
    float h0a=cb1s[lane],h1a=cb1s[lane],h2a=cb1s[lane],h3a=cb1s[lane];
    for (int k = 0; k < 96; ++k) {
      float w = c1t[k*64+lane];
      h0a += w*cmb[wv][0][k]; h1a += w*cmb[wv][1][k];
      h2a += w*cmb[wv][2][k]; h3a += w*cmb[wv][3][k];
    }
    h2b[wv][0][lane]=ftanh(h0a); h2b[wv][1][lane]=ftanh(h1a);
    h2b[wv][2][lane]=ftanh(h2a); h2b[wv][3][lane]=ftanh(h3a);
    __syncthreads();
    float a0=cb2s[lane],a1=cb2s[lane],a2=cb2s[lane],a3=cb2s[lane];
    for (int k = 0; k < 64; ++k) {
      float w = c2t[k*64+lane];
      a0 += w*h2b[wv][0][k]; a1 += w*h2b[wv][1][k];
      a2 += w*h2b[wv][2][k]; a3 += w*h2b[wv][3][k];
    }
    float m0=wmax(a0), m1=wmax(a1), m2=wmax(a2), m3=wmax(a3);
    float e0=__expf(a0-m0), e1=__expf(a1-m1), e2=__expf(a2-m2), e3=__expf(a3-m3);
    float s0=wsum(e0), s1=wsum(e1), s2=wsum(e2), s3=wsum(e3);
    float f0v=e0/s0, f1v=e1/s1, f2v=e2/s2, f3v=e3/s3;
    size_t R;
    R=R0+0; fw_out[R*64+lane]=f0v; wx[R*64+lane]=x[R*64+lane]*f0v;
    R=R0+1; fw_out[R*64+lane]=f1v; wx[R*64+lane]=x[R*64+lane]*f1v;
    R=R0+2; fw_out[R*64+lane]=f2v; wx[R*64+lane]=x[R*64+lane]*f2v;
    R=R0+3; fw_out[R*64+lane]=f3v; wx[R*64+lane]=x[R*64+lane]*f3v;
    __syncthreads();
  }
}

// ================= MFMA encoder LSTM (swapped operands) =================
// Also emits ench: f16 copy of enc, row-padded to 112 (units 100..111 zeroed
// by the invalid lanes) for the k_ts MFMA GEMM. k=112..127 of the last K
// chunk is a register-zero fragment in k_ts — never loaded from memory.
__global__ __launch_bounds__(448, 2) void k_enc_mfma(const float* __restrict__ wx,
    const float* __restrict__ Wih, const float* __restrict__ Whh,
    const float* __restrict__ bih, const float* __restrict__ bhh,
    float* __restrict__ enc, _Float16* __restrict__ ench){
  __shared__ __align__(16) _Float16 hbuf[2][16*128];
  __shared__ __align__(16) _Float16 xst[2][16*64];
  int tid = threadIdx.x;
  int w = tid >> 6, l = tid & 63;
  int lm = l & 15, lq = l >> 4;
  int b0 = blockIdx.x * 16;
  int au = w*16 + lm;
  bool avalid = au < 100;
  int u0 = w*16 + lq*4;
  bool uvalid = (u0 + 3) < 100;
  h8 wfr[4][6];
#pragma unroll
  for (int tt=0; tt<4; ++tt){
    int row = tt*100 + au;
#pragma unroll
    for (int cc=0; cc<6; ++cc){
      h8 f;
#pragma unroll
      for (int j=0;j<8;++j){
        int kg = cc*32 + lq*8 + j;
        float v = 0.f;
        if (avalid){
          if (kg < 64) v = Wih[(size_t)row*64 + kg];
          else { int kh = kg - 64; if (kh < 100) v = Whh[(size_t)row*100 + kh]; }
        }
        f[j] = (_Float16)v;
      }
      wfr[tt][cc] = f;
    }
  }
  f4v biasv[4];
#pragma unroll
  for (int tt=0; tt<4; ++tt){
    if (uvalid){
      float4 bi = *(const float4*)&bih[tt*100 + u0];
      float4 bh = *(const float4*)&bhh[tt*100 + u0];
      f4v bv2 = {bi.x+bh.x, bi.y+bh.y, bi.z+bh.z, bi.w+bh.w};
      biasv[tt] = bv2;
    } else { f4v z = {0,0,0,0}; biasv[tt] = z; }
  }
  for (int i = tid; i < 2*16*128; i += 448) hbuf[0][i] = (_Float16)0.f;
  int sm = tid >> 4, skq = tid & 15;
  if (tid < 256){
    float4 xv0 = *(const float4*)(wx + ((size_t)(b0+sm)*SS + 0)*FF + skq*4);
    h4 p = {(_Float16)xv0.x,(_Float16)xv0.y,(_Float16)xv0.z,(_Float16)xv0.w};
    *(h4*)&xst[0][sm*64 + (((skq>>1) ^ (sm&7))<<3) + (skq&1)*4] = p;
  }
  float cst[4] = {0.f,0.f,0.f,0.f};
  int hwaddr = lm*128 + (((2*w + (lq>>1)) ^ (lm&7))<<3) + (lq&1)*4;
  __syncthreads();
  for (int t = 0; t < SS; ++t){
    int cur = t & 1, nxt = cur ^ 1;
    float4 xv;
    bool doPref = (tid < 256) && (t < SS-1);
    if (doPref) xv = *(const float4*)(wx + ((size_t)(b0+sm)*SS + (t+1))*FF + skq*4);
    h8 bact[6];
#pragma unroll
    for (int cc=0; cc<2; ++cc)
      bact[cc] = *(const h8*)&xst[cur][lm*64 + (((cc*4+lq) ^ (lm&7))<<3)];
#pragma unroll
    for (int cc=0; cc<4; ++cc)
      bact[2+cc] = *(const h8*)&hbuf[cur][lm*128 + (((cc*4+lq) ^ (lm&7))<<3)];
    f4v acc[4];
#pragma unroll
    for (int tt=0; tt<4; ++tt){
      f4v a = biasv[tt];
#pragma unroll
      for (int cc=0; cc<6; ++cc)
        a = __builtin_amdgcn_mfma_f32_16x16x32_f16(wfr[tt][cc], bact[cc], a, 0, 0, 0);
      acc[tt] = a;
    }
    float hn[4];
#pragma unroll
    for (int r=0;r<4;++r){
      float cn = sigmf(acc[1][r])*cst[r] + sigmf(acc[0][r])*ftanh(acc[2][r]);
      hn[r] = sigmf(acc[3][r])*ftanh(cn);
      cst[r] = cn;
    }
    if (uvalid){
      h4 hp = {(_Float16)hn[0],(_Float16)hn[1],(_Float16)hn[2],(_Float16)hn[3]};
      *(h4*)&hbuf[nxt][hwaddr] = hp;
      float4 st; st.x=hn[0]; st.y=hn[1]; st.z=hn[2]; st.w=hn[3];
      *(float4*)&enc[((size_t)(b0+lm)*SS + t)*HH + u0] = st;
      *(h4*)&ench[((size_t)(b0+lm)*SS + t)*112 + u0] = hp;
    } else {
      // u0 in {100,104,108}: zero the f16 pad so k_ts MFMA never sees garbage
      h4 z = {(_Float16)0.f,(_Float16)0.f,(_Float16)0.f,(_Float16)0.f};
      *(h4*)&ench[((size_t)(b0+lm)*SS + t)*112 + u0] = z;
    }
    if (doPref){
      h4 p = {(_Float16)xv.x,(_Float16)xv.y,(_Float16)xv.z,(_Float16)xv.w};
      *(h4*)&xst[nxt][sm*64 + (((skq>>1) ^ (sm&7))<<3) + (skq&1)*4] = p;
    }
    LDS_BARRIER();
  }
}

// ================= ts GEMM: ts[b,s] = aW2 @ tanh(aW1 @ enc_row + ab1) + ab2 ========
// M = B*S rows (ench f16, 112-padded), N = 64, K = 100->128 (chunk 3 half-zero).
// A-frags: direct 16B global loads (no LDS). B (aW1) + ab1/aW2 in registers.
__global__ __launch_bounds__(256) void k_ts(const _Float16* __restrict__ ench,
    const float* __restrict__ aW1, const float* __restrict__ ab1,
    const float* __restrict__ aW2, const float* __restrict__ ab2,
    float* __restrict__ ts){
  int tid = threadIdx.x, wv = tid>>6, l = tid&63, lm = l&15, lq = l>>4;
  h8 bfr[4][4];
#pragma unroll
  for (int nt=0; nt<4; ++nt){
    int n = nt*16 + lm;
#pragma unroll
    for (int cc=0; cc<4; ++cc){
      h8 f;
#pragma unroll
      for (int j=0;j<8;++j){
        int k = cc*32 + lq*8 + j;
        f[j] = (_Float16)((k<100) ? aW1[n*100+k] : 0.f);
      }
      bfr[nt][cc]=f;
    }
  }
  float ab1v[4], aw2v[4];
#pragma unroll
  for (int nt=0; nt<4; ++nt){ ab1v[nt] = ab1[nt*16+lm]; aw2v[nt] = aW2[nt*16+lm]; }
  float ab2v = ab2[0];
  int tile0 = (blockIdx.x*4 + wv)*4;
#pragma unroll
  for (int i=0;i<4;++i){
    int M0 = (tile0+i)*16;
    const _Float16* rowp = ench + (size_t)(M0+lm)*112;
    h8 afr[4];
#pragma unroll
    for (int cc=0; cc<3; ++cc)
      afr[cc] = *(const h8*)(rowp + cc*32 + lq*8);
    if (lq < 2) afr[3] = *(const h8*)(rowp + 96 + lq*8);
    else { h8 z={0,0,0,0,0,0,0,0}; afr[3]=z; }
    f4v acc[4];
#pragma unroll
    for (int nt=0; nt<4; ++nt){
      f4v a = {ab1v[nt],ab1v[nt],ab1v[nt],ab1v[nt]};
#pragma unroll
      for (int cc=0; cc<4; ++cc)
        a = __builtin_amdgcn_mfma_f32_16x16x32_f16(afr[cc], bfr[nt][cc], a, 0,0,0);
      acc[nt]=a;
    }
    float p[4];
#pragma unroll
    for (int r=0;r<4;++r){
      p[r] = aw2v[0]*ftanh(acc[0][r]) + aw2v[1]*ftanh(acc[1][r])
           + aw2v[2]*ftanh(acc[2][r]) + aw2v[3]*ftanh(acc[3][r]);
#pragma unroll
      for (int m=1;m<16;m<<=1) p[r] += __shfl_xor(p[r], m, 64);
    }
    if (lm==0){
      float4 st; st.x=p[0]+ab2v; st.y=p[1]+ab2v; st.z=p[2]+ab2v; st.w=p[3]+ab2v;
      *(float4*)&ts[M0 + lq*4] = st;
    }
  }
}

// ------- per-b: softmax(ts) over S, ctx, bott, dh0, dc0, decpre -------
__global__ __launch_bounds__(256) void k_attn2(const float* __restrict__ enc,
    const float* __restrict__ ts,
    const float* __restrict__ bW, const float* __restrict__ bb_,
    const float* __restrict__ h0W, const float* __restrict__ h0b,
    const float* __restrict__ c0W, const float* __restrict__ c0b,
    const float* __restrict__ dWih, const float* __restrict__ dbih, const float* __restrict__ dbhh,
    float* __restrict__ tw_out, float* __restrict__ dh0, float* __restrict__ dc0,
    float* __restrict__ decpre){
  __shared__ float tsb[SS];
  __shared__ float ctxb[HH];
  __shared__ float bottb[32];
  __shared__ float red[8];
  int tid = threadIdx.x, wv = tid>>6, lane = tid&63;
  int b = blockIdx.x;
  const float* encb = enc + (size_t)b*SS*HH;
  float tv = (tid < SS) ? ts[(size_t)b*SS + tid] : -1e30f;
  float m = wmax(tv);
  if (lane==0) red[wv]=m;
  __syncthreads();
  m = fmaxf(fmaxf(red[0],red[1]), fmaxf(red[2],red[3]));
  float e = (tid < SS) ? __expf(tv - m) : 0.f;
  float sm = wsum(e);
  if (lane==0) red[4+wv]=sm;
  __syncthreads();
  float denom = red[4]+red[5]+red[6]+red[7];
  if (tid < SS){
    float twv = e/denom;
    tw_out[(size_t)b*SS + tid] = twv;
    tsb[tid] = twv;
  }
  __syncthreads();
  if (tid < HH){
    float a = 0.f;
#pragma unroll 4
    for (int s=0;s<SS;++s) a += tsb[s]*encb[s*HH + tid];
    ctxb[tid]=a;
  }
  __syncthreads();
  if (tid < 32){
    float a = bb_[tid];
    const float* wr = bW + tid*HH;
    for (int k=0;k<HH;++k) a += wr[k]*ctxb[k];
    bottb[tid]=a;
  }
  __syncthreads();
  if (tid < HH){
    float a = h0b[tid];
    const float* wr = h0W + tid*32;
#pragma unroll
    for (int k=0;k<32;++k) a += wr[k]*bottb[k];
    dh0[(size_t)b*HH + tid] = a;
  } else if (tid < 200){
    int jj = tid-100;
    float a = c0b[jj];
    const float* wr = c0W + jj*32;
#pragma unroll
    for (int k=0;k<32;++k) a += wr[k]*bottb[k];
    dc0[(size_t)b*HH + jj] = a;
  }
  {
    int jj = tid;
    float a = dbih[jj]+dbhh[jj];
    const float* wr = dWih + jj*32;
#pragma unroll
    for (int k=0;k<32;++k) a += wr[k]*bottb[k];
    decpre[(size_t)b*400 + jj] = a;
    jj = tid + 256;
    if (jj < 400){
      float a2v = dbih[jj]+dbhh[jj];
      const float* wr2 = dWih + jj*32;
#pragma unroll
      for (int k=0;k<32;++k) a2v += wr2[k]*bottb[k];
      decpre[(size_t)b*400 + jj] = a2v;
    }
  }
}

// ================= MFMA decoder LSTM (swapped operands) =================
__global__ __launch_bounds__(448, 2) void k_dec_mfma(const float* __restrict__ decpre,
    const float* __restrict__ Whh,
    const float* __restrict__ dh0, const float* __restrict__ dc0,
    float* __restrict__ dec){
  __shared__ __align__(16) _Float16 hbuf[2][16*128];
  int tid = threadIdx.x;
  int w = tid >> 6, l = tid & 63;
  int lm = l & 15, lq = l >> 4;
  int b0 = blockIdx.x * 16;
  int au = w*16 + lm;
  bool avalid = au < 100;
  int u0 = w*16 + lq*4;
  bool uvalid = (u0 + 3) < 100;
  h8 wfr[4][4];
#pragma unroll
  for (int tt = 0; tt < 4; ++tt){
    int row = tt*100 + au;
#pragma unroll
    for (int cc = 0; cc < 4; ++cc){
      h8 f;
#pragma unroll
      for (int j = 0; j < 8; ++j){
        int kh = cc*32 + lq*8 + j;
        float v = (avalid && kh < 100) ? Whh[(size_t)row*100 + kh] : 0.f;
        f[j] = (_Float16)v;
      }
      wfr[tt][cc] = f;
    }
  }
  f4v pre[4];
  float cst[4] = {0.f,0.f,0.f,0.f};
  if (uvalid){
#pragma unroll
    for (int tt = 0; tt < 4; ++tt){
      float4 p = *(const float4*)&decpre[(size_t)(b0+lm)*400 + tt*100 + u0];
      f4v pv = {p.x, p.y, p.z, p.w};
      pre[tt] = pv;
    }
    float4 c4 = *(const float4*)&dc0[(size_t)(b0+lm)*100 + u0];
    cst[0]=c4.x; cst[1]=c4.y; cst[2]=c4.z; cst[3]=c4.w;
  } else {
    f4v z = {0,0,0,0};
#pragma unroll
    for (int tt = 0; tt < 4; ++tt) pre[tt] = z;
  }
  for (int i = tid; i < 16*128; i += 448) hbuf[1][i] = (_Float16)0.f;
  for (int idx = tid; idx < 16*128; idx += 448){
    int m = idx >> 7, u2 = idx & 127;
    float v = (u2 < 100) ? dh0[(size_t)(b0+m)*HH + u2] : 0.f;
    hbuf[0][m*128 + (((u2>>3) ^ (m&7))<<3) + (u2&7)] = (_Float16)v;
  }
  int hwaddr = lm*128 + (((2*w + (lq>>1)) ^ (lm&7))<<3) + (lq&1)*4;
  __syncthreads();
  for (int t = 0; t < SS; ++t){
    int cur = t & 1, nxt = cur ^ 1;
    h8 bact[4];
#pragma unroll
    for (int cc = 0; cc < 4; ++cc)
      bact[cc] = *(const h8*)&hbuf[cur][lm*128 + (((cc*4+lq) ^ (lm&7))<<3)];
    f4v acc[4];
#pragma unroll
    for (int tt = 0; tt < 4; ++tt){
      f4v a = pre[tt];
#pragma unroll
      for (int cc = 0; cc < 4; ++cc)
        a = __builtin_amdgcn_mfma_f32_16x16x32_f16(wfr[tt][cc], bact[cc], a, 0, 0, 0);
      acc[tt] = a;
    }
    float hn[4];
#pragma unroll
    for (int r=0;r<4;++r){
      float cn = sigmf(acc[1][r])*cst[r] + sigmf(acc[0][r])*ftanh(acc[2][r]);
      hn[r] = sigmf(acc[3][r])*ftanh(cn);
      cst[r] = cn;
    }
    if (uvalid){
      h4 hp = {(_Float16)hn[0],(_Float16)hn[1],(_Float16)hn[2],(_Float16)hn[3]};
      *(h4*)&hbuf[nxt][hwaddr] = hp;
      float4 st; st.x=hn[0]; st.y=hn[1]; st.z=hn[2]; st.w=hn[3];
      *(float4*)&dec[((size_t)(b0+lm)*SS + t)*HH + u0] = st;
    }
    LDS_BARRIER();
  }
}

// ------------- out = dec @ oW^T + ob -------------
__global__ __launch_bounds__(256) void k_out(const float* __restrict__ dec,
    const float* __restrict__ oW, const float* __restrict__ ob, float* __restrict__ out0){
  __shared__ float oWt[100*64];
  __shared__ float dsr[64*100];
  int tid=threadIdx.x;
  size_t R0 = (size_t)blockIdx.x*64;
  for (int i=tid;i<6400;i+=256){ int j=i/100,k=i%100; oWt[k*64+j]=oW[i]; }
  for (int i=tid;i<6400;i+=256) dsr[i]=dec[R0*100 + i];
  __syncthreads();
  int j = tid&63, rb = tid>>6;
  float acc[16];
#pragma unroll
  for (int i=0;i<16;++i) acc[i]=0.f;
  for (int k=0;k<100;++k){
    float w = oWt[k*64+j];
#pragma unroll
    for (int i=0;i<16;++i) acc[i] += w*dsr[(rb + i*4)*100 + k];
  }
  float obv = ob[j];
#pragma unroll
  for (int i=0;i<16;++i) out0[(R0 + rb + i*4)*64 + j] = acc[i] + obv;
}

extern "C" void kernel_launch(void* const* d_in, const int* in_sizes, int n_in,
                              void* d_out, int out_size, void* d_ws, size_t ws_size,
                              hipStream_t stream) {
  const float* x    = (const float*)d_in[0];
  const float* c1w  = (const float*)d_in[1];
  const float* c1b  = (const float*)d_in[2];
  const float* c2w  = (const float*)d_in[3];
  const float* c2b  = (const float*)d_in[4];
  const float* fW1  = (const float*)d_in[5];
  const float* fb1  = (const float*)d_in[6];
  const float* fW2  = (const float*)d_in[7];
  const float* fb2  = (const float*)d_in[8];
  const float* cW1  = (const float*)d_in[9];
  const float* cb1  = (const float*)d_in[10];
  const float* cW2  = (const float*)d_in[11];
  const float* cb2  = (const float*)d_in[12];
  const float* eWih = (const float*)d_in[13];
  const float* eWhh = (const float*)d_in[14];
  const float* ebih = (const float*)d_in[15];
  const float* ebhh = (const float*)d_in[16];
  const float* aW1  = (const float*)d_in[17];
  const float* ab1  = (const float*)d_in[18];
  const float* aW2  = (const float*)d_in[19];
  const float* ab2  = (const float*)d_in[20];
  const float* bW   = (const float*)d_in[21];
  const float* bb   = (const float*)d_in[22];
  const float* h0W  = (const float*)d_in[23];
  const float* h0b  = (const float*)d_in[24];
  const float* c0W  = (const float*)d_in[25];
  const float* c0b  = (const float*)d_in[26];
  const float* dWih = (const float*)d_in[27];
  const float* dWhh = (const float*)d_in[28];
  const float* dbih = (const float*)d_in[29];
  const float* dbhh = (const float*)d_in[30];
  const float* oW   = (const float*)d_in[31];
  const float* ob   = (const float*)d_in[32];

  float* out0   = (float*)d_out;
  float* out_tw = out0 + (size_t)BB*SS*FF;
  float* out_fw = out_tw + (size_t)BB*SS;

  char* ws = (char*)d_ws;
  float*  gram   = (float*) (ws + 0);           // 16.78 MB (reused as ts after conv1)
  __half* pool1  = (__half*)(ws + 16777216);    // 33.55 MB (channel-last [b][p][ic])
  float*  proc   = (float*) (ws + 50331648);    // 0.13 MB
  float*  fsbuf  = (float*) (ws + 50462720);    // 33.55 MB (reused as ench after attnmlp)
  float*  wx     = (float*) (ws + 84017152);    // 33.55 MB
  float*  enc    = (float*) (ws + 117571584);   // 52.43 MB
  float*  dh0    = (float*) (ws + 170000384);   // 0.41 MB
  float*  dc0    = (float*) (ws + 170409984);   // 0.41 MB
  float*  decpre = (float*) (ws + 170819584);   // 1.64 MB
  float*  dec    = (float*) (ws + 172457984);   // 52.43 MB  (end ~224.9 MB)
  float*     tsbuf = (float*)gram;              // 0.52 MB (gram dead after conv1)
  _Float16*  ench  = (_Float16*)fsbuf;          // 29.36 MB (fsbuf dead after attnmlp)

  k_gram<<<BB, 256, 0, stream>>>(x, gram);
  k_conv1pool<<<BB, 256, 0, stream>>>(gram, c1w, c1b, pool1);
  k_conv2mfma<<<BB, 512, 0, stream>>>(pool1, c2w, c2b, proc);
  k_fs<<<2048, 256, 0, stream>>>(x, fW1, fb1, fW2, fb2, fsbuf);
  k_attnmlp<<<2048, 256, 0, stream>>>(x, fsbuf, proc, cW1, cb1, cW2, cb2, out_fw, wx);
  k_enc_mfma<<<64, 448, 0, stream>>>(wx, eWih, eWhh, ebih, ebhh, enc, ench);
  k_ts<<<512, 256, 0, stream>>>(ench, aW1, ab1, aW2, ab2, tsbuf);
  k_attn2<<<BB, 256, 0, stream>>>(enc, tsbuf, bW, bb, h0W, h0b, c0W, c0b,
                                  dWih, dbih, dbhh, out_tw, dh0, dc0, decpre);
  k_dec_mfma<<<64, 448, 0, stream>>>(decpre, dWhh, dh0, dc0, dec);
  k_out<<<2048, 256, 0, stream>>>(dec, oW, ob, out0);
}